// Round 1
// baseline (1786.046 us; speedup 1.0000x reference)
//
#include <hip/hip_runtime.h>
#include <cstdint>

// ---------------- bf16 helpers ----------------
__device__ __forceinline__ float b2f(unsigned short u) {
    unsigned int t = ((unsigned int)u) << 16;
    float f;
    __builtin_memcpy(&f, &t, 4);
    return f;
}
__device__ __forceinline__ unsigned short f2b(float f) {
    unsigned int u;
    __builtin_memcpy(&u, &f, 4);
    unsigned int r = (u + 0x7FFFu + ((u >> 16) & 1u)) >> 16;
    return (unsigned short)r;
}
__device__ __forceinline__ float2 bpair(unsigned int u) {
    float2 r;
    unsigned int lo = u << 16;
    unsigned int hi = u & 0xFFFF0000u;
    __builtin_memcpy(&r.x, &lo, 4);
    __builtin_memcpy(&r.y, &hi, 4);
    return r;
}
// packed f32x2 -> bf16x2 (RNE), single VALU op
__device__ __forceinline__ unsigned int cvtpk(float lo, float hi) {
    unsigned int r;
    asm("v_cvt_pk_bf16_f32 %0, %1, %2" : "=v"(r) : "v"(lo), "v"(hi));
    return r;
}

typedef __attribute__((ext_vector_type(8))) short bf16x8;
typedef __attribute__((ext_vector_type(4))) float f32x4;

__device__ __forceinline__ bf16x8 pack4(unsigned a, unsigned b, unsigned c, unsigned d) {
    union { uint4 u; bf16x8 v; } x;
    x.u = (uint4){a, b, c, d};
    return x.v;
}

#define LOG2E 1.4426950408889634f
#define SC2   0.2550348595f   /* (1/sqrt(32)) * log2(e) */

// ---------------- weight transpose + fp32->bf16 convert (once per call) ----------------
__global__ void transcvt_k(const float* __restrict__ in,
                           unsigned short* __restrict__ out, int R, int C,
                           int in_z, int out_z) {
    __shared__ float tile[32][33];
    in += (size_t)blockIdx.z * in_z;
    out += (size_t)blockIdx.z * out_z;
    const int c0 = blockIdx.x * 32, r0 = blockIdx.y * 32;
    const int tx = threadIdx.x, ty = threadIdx.y;
#pragma unroll
    for (int i = 0; i < 32; i += 8)
        tile[ty + i][tx] = in[(size_t)(r0 + ty + i) * C + c0 + tx];
    __syncthreads();
#pragma unroll
    for (int i = 0; i < 32; i += 8)
        out[(size_t)(c0 + ty + i) * R + r0 + tx] = f2b(tile[tx][ty + i]);
}

// ---------------- sph -> bf16 * log2e (once per call) ----------------
__global__ __launch_bounds__(256) void sph_cvt(const float* __restrict__ in,
                                               unsigned short* __restrict__ out) {
    const size_t idx = (size_t)blockIdx.x * 256 + threadIdx.x;
    const float4 a = ((const float4*)in)[idx * 2];
    const float4 b = ((const float4*)in)[idx * 2 + 1];
    uint4 o;
    o.x = (unsigned)f2b(a.x * LOG2E) | ((unsigned)f2b(a.y * LOG2E) << 16);
    o.y = (unsigned)f2b(a.z * LOG2E) | ((unsigned)f2b(a.w * LOG2E) << 16);
    o.z = (unsigned)f2b(b.x * LOG2E) | ((unsigned)f2b(b.y * LOG2E) << 16);
    o.w = (unsigned)f2b(b.z * LOG2E) | ((unsigned)f2b(b.w * LOG2E) << 16);
    ((uint4*)out)[idx] = o;
}

// ---------------- GEMM: C[M,N] = A[M,K] @ Wt[N,K]^T + bias (+gelu) ----------------
template <int AF32, int QKVB>
__global__ __launch_bounds__(256) void gemm_bias_kernel(
    const void* __restrict__ Ap, const unsigned short* __restrict__ Wt,
    const float* __restrict__ biasQ, const float* __restrict__ biasK,
    const float* __restrict__ biasV, unsigned short* __restrict__ C,
    int M, int N, int K, int do_gelu) {
    __shared__ unsigned short As[64 * 40];
    __shared__ unsigned short Bs[64 * 40];
    const int tid = threadIdx.x;
    const int lane = tid & 63, wid = tid >> 6;
    const int m0 = blockIdx.y * 64, n0 = blockIdx.x * 64;
    const int wm = (wid >> 1) * 32, wn = (wid & 1) * 32;
    const int quad = lane >> 4, mrow = lane & 15;
    f32x4 acc[2][2] = {};
    const int arow = tid >> 2, ak = (tid & 3) << 3;
    const unsigned short* Bg = Wt + (size_t)(n0 + arow) * K + ak;
    const float* Agf = (const float*)Ap + (size_t)(m0 + arow) * K + ak;
    const unsigned short* Agb = (const unsigned short*)Ap + (size_t)(m0 + arow) * K + ak;

    typedef __attribute__((ext_vector_type(8))) short short8;
    for (int kb = 0; kb < K; kb += 32) {
        if (AF32) {
            float4 f0 = *(const float4*)(Agf + kb);
            float4 f1 = *(const float4*)(Agf + kb + 4);
            short8 t;
            t[0] = (short)f2b(f0.x); t[1] = (short)f2b(f0.y);
            t[2] = (short)f2b(f0.z); t[3] = (short)f2b(f0.w);
            t[4] = (short)f2b(f1.x); t[5] = (short)f2b(f1.y);
            t[6] = (short)f2b(f1.z); t[7] = (short)f2b(f1.w);
            *(short8*)&As[arow * 40 + ak] = t;
        } else {
            *(uint4*)&As[arow * 40 + ak] = *(const uint4*)(Agb + kb);
        }
        *(uint4*)&Bs[arow * 40 + ak] = *(const uint4*)(Bg + kb);
        __syncthreads();
        bf16x8 a0 = *(const bf16x8*)&As[(wm + mrow) * 40 + quad * 8];
        bf16x8 a1 = *(const bf16x8*)&As[(wm + 16 + mrow) * 40 + quad * 8];
        bf16x8 b0 = *(const bf16x8*)&Bs[(wn + mrow) * 40 + quad * 8];
        bf16x8 b1 = *(const bf16x8*)&Bs[(wn + 16 + mrow) * 40 + quad * 8];
        acc[0][0] = __builtin_amdgcn_mfma_f32_16x16x32_bf16(a0, b0, acc[0][0], 0, 0, 0);
        acc[0][1] = __builtin_amdgcn_mfma_f32_16x16x32_bf16(a0, b1, acc[0][1], 0, 0, 0);
        acc[1][0] = __builtin_amdgcn_mfma_f32_16x16x32_bf16(a1, b0, acc[1][0], 0, 0, 0);
        acc[1][1] = __builtin_amdgcn_mfma_f32_16x16x32_bf16(a1, b1, acc[1][1], 0, 0, 0);
        __syncthreads();
    }
    const float* bp;
    if (QKVB) {
        const int bsel = n0 >> 8;
        bp = bsel == 0 ? biasQ : (bsel == 1 ? biasK : biasV);
    } else {
        bp = biasQ;
    }
#pragma unroll
    for (int i = 0; i < 2; i++)
#pragma unroll
        for (int j = 0; j < 2; j++) {
            const int col = n0 + wn + j * 16 + mrow;
            const float bv = QKVB ? bp[col & 255] : bp[col];
#pragma unroll
            for (int r = 0; r < 4; r++) {
                const int row = m0 + wm + i * 16 + quad * 4 + r;
                float v = acc[i][j][r] + bv;
                if (do_gelu) v = 0.5f * v * (1.0f + erff(v * 0.70710678118654752f));
                C[(size_t)row * N + col] = f2b(v);
            }
        }
}

// ---------------- attention: swapped-QK^T flash MFMA, in-register P ----------------
// S^T = mfma(K_frag, Q_frag): lane (quad,lq) holds P for q = lq (one row!) and
// keys 16g+4*quad+{0..3} per group g. Softmax is then lane-local: sph bias loads
// become 8B vector loads, P->bf16 is v_cvt_pk_bf16_f32 pairs, and the PV
// A-fragment is assembled in registers (no P LDS round-trip at all).
// V LDS columns are stored in "slot" order (key bits {a,h,q,r} -> slot {a,q,h,r})
// so the register key order matches the MFMA k-slot order; pure address
// permutation computed once outside the loop.
template <int SPHB16>
__global__ __launch_bounds__(256) void attn_mfma(
    const unsigned short* __restrict__ Qb, const unsigned short* __restrict__ Kb,
    const unsigned short* __restrict__ Vb, const float* __restrict__ sphf,
    const unsigned short* __restrict__ sphb, unsigned short* __restrict__ Ctx) {
    __shared__ unsigned short Ks[64 * 40];
    __shared__ unsigned short Vt[32 * 72];

    const int tid = threadIdx.x, lane = tid & 63, wid = tid >> 6;
    const int quad = lane >> 4, lq = lane & 15;
    const int bid = blockIdx.x;
    const int h = bid >> 8, b = (bid >> 5) & 7, qt = bid & 31;
    const int q0 = qt * 64;
    const size_t bS = (size_t)b * 2048;

    // staging addresses (QKV stride 768)
    const int skey = tid >> 2, sdg = (tid & 3) << 3;
    const unsigned short* kgp = Kb + (bS + skey) * 768 + h * 32 + sdg;
    const int vkp = tid & 31, vdg = (tid >> 5) << 2;
    const unsigned short* vgp = Vb + (bS + 2 * vkp) * 768 + h * 32 + vdg;
    // slot permutation for the even key of this thread's V column pair
    const int vk2 = 2 * vkp;
    const int vslot = (vk2 & 0x23) | ((vk2 & 0x0C) << 1) | ((vk2 & 0x10) >> 2);

    // Q fragment (B-operand: col = lq = q-row, k = quad*8+j), persistent
    const bf16x8 qf = *(const bf16x8*)(Qb + (bS + q0 + wid * 16 + lq) * 768 + h * 32 + quad * 8);

    // sph bias: single row q0+wid*16+lq per lane, cols k0 + 16g + 4*quad + {0..3}
    const size_t sbase = ((size_t)b * 2048 + q0 + wid * 16 + lq) * 2048 + 4 * quad;
    const float* spf_ = sphf + sbase;
    const unsigned short* spb_ = sphb + sbase;

    float l_lane = 0.f;
    f32x4 o0 = {}, o1 = {};
    const f32x4 zf = {};

    for (int kt = 0; kt < 32; ++kt) {
        const int k0 = kt * 64;
        __syncthreads();                        // protect Ks/Vt reuse
        *(uint4*)&Ks[skey * 40 + sdg] = *(const uint4*)(kgp + (size_t)k0 * 768);
        {
            uint2 va = *(const uint2*)(vgp + (size_t)k0 * 768);
            uint2 vb2 = *(const uint2*)(vgp + (size_t)k0 * 768 + 768);
            *(unsigned int*)&Vt[(vdg + 0) * 72 + vslot] = (va.x & 0xFFFFu) | (vb2.x << 16);
            *(unsigned int*)&Vt[(vdg + 1) * 72 + vslot] = (va.x >> 16) | (vb2.x & 0xFFFF0000u);
            *(unsigned int*)&Vt[(vdg + 2) * 72 + vslot] = (va.y & 0xFFFFu) | (vb2.y << 16);
            *(unsigned int*)&Vt[(vdg + 3) * 72 + vslot] = (va.y >> 16) | (vb2.y & 0xFFFF0000u);
        }
        __syncthreads();

        // S^T = K Q^T per 16-key group; p = exp2(qk*SC2 + sph*log2e) in-lane
        unsigned int w[4][2];
#pragma unroll
        for (int g = 0; g < 4; ++g) {
            const bf16x8 kf = *(const bf16x8*)&Ks[(16 * g + lq) * 40 + quad * 8];
            const f32x4 s = __builtin_amdgcn_mfma_f32_16x16x32_bf16(kf, qf, zf, 0, 0, 0);
            float sb0, sb1, sb2, sb3;
            if (SPHB16) {
                const uint2 su = *(const uint2*)(spb_ + k0 + 16 * g);
                const float2 lo = bpair(su.x), hi = bpair(su.y);
                sb0 = lo.x; sb1 = lo.y; sb2 = hi.x; sb3 = hi.y;
            } else {
                const float4 sf = *(const float4*)(spf_ + k0 + 16 * g);
                sb0 = sf.x * LOG2E; sb1 = sf.y * LOG2E;
                sb2 = sf.z * LOG2E; sb3 = sf.w * LOG2E;
            }
            const float p0 = __builtin_amdgcn_exp2f(fmaf(s[0], SC2, sb0));
            const float p1 = __builtin_amdgcn_exp2f(fmaf(s[1], SC2, sb1));
            const float p2 = __builtin_amdgcn_exp2f(fmaf(s[2], SC2, sb2));
            const float p3 = __builtin_amdgcn_exp2f(fmaf(s[3], SC2, sb3));
            l_lane += (p0 + p1) + (p2 + p3);
            w[g][0] = cvtpk(p0, p1);
            w[g][1] = cvtpk(p2, p3);
        }

        // PV: A-fragment straight from registers (keys already in slot order)
        const bf16x8 pf0 = pack4(w[0][0], w[0][1], w[1][0], w[1][1]);
        const bf16x8 pf1 = pack4(w[2][0], w[2][1], w[3][0], w[3][1]);
        o0 = __builtin_amdgcn_mfma_f32_16x16x32_bf16(
            pf0, *(const bf16x8*)&Vt[(0  + lq) * 72 + 0 * 32 + quad * 8], o0, 0, 0, 0);
        o1 = __builtin_amdgcn_mfma_f32_16x16x32_bf16(
            pf0, *(const bf16x8*)&Vt[(16 + lq) * 72 + 0 * 32 + quad * 8], o1, 0, 0, 0);
        o0 = __builtin_amdgcn_mfma_f32_16x16x32_bf16(
            pf1, *(const bf16x8*)&Vt[(0  + lq) * 72 + 1 * 32 + quad * 8], o0, 0, 0, 0);
        o1 = __builtin_amdgcn_mfma_f32_16x16x32_bf16(
            pf1, *(const bf16x8*)&Vt[(16 + lq) * 72 + 1 * 32 + quad * 8], o1, 0, 0, 0);
    }

    // epilogue: l is per-lane (q = lq); sum the 4 quad-partials, then fetch the
    // inverse for this lane's output rows (q = quad*4+r) via lane shuffle.
    l_lane += __shfl_xor(l_lane, 16);
    l_lane += __shfl_xor(l_lane, 32);
    const float inv = 1.f / l_lane;
    unsigned short* op = Ctx + (bS + q0 + wid * 16 + quad * 4) * 256 + h * 32;
#pragma unroll
    for (int r = 0; r < 4; ++r) {
        const float ir = __shfl(inv, quad * 4 + r);
        op[r * 256 + lq]      = f2b(o0[r] * ir);
        op[r * 256 + 16 + lq] = f2b(o1[r] * ir);
    }
}

// ---------------- fused residual + LayerNorm (fp32 stream) ----------------
__global__ __launch_bounds__(256) void add_ln_kernel(
    const float* __restrict__ x, const unsigned short* __restrict__ r,
    const float* __restrict__ g, const float* __restrict__ be,
    float* __restrict__ out) {
    const int lane = threadIdx.x & 63, wid = threadIdx.x >> 6;
    const size_t row = (size_t)blockIdx.x * 4 + wid;
    float4 xv = *(const float4*)(x + row * 256 + lane * 4);
    uint2 ru = *(const uint2*)(r + row * 256 + lane * 4);
    float2 ra = bpair(ru.x), rb = bpair(ru.y);
    float v[4] = {xv.x + ra.x, xv.y + ra.y, xv.z + rb.x, xv.w + rb.y};
    float sum = v[0] + v[1] + v[2] + v[3];
#pragma unroll
    for (int off = 32; off; off >>= 1) sum += __shfl_xor(sum, off);
    const float mu = sum * (1.f / 256.f);
    float sq = 0.f;
#pragma unroll
    for (int i = 0; i < 4; i++) { float d = v[i] - mu; sq += d * d; }
#pragma unroll
    for (int off = 32; off; off >>= 1) sq += __shfl_xor(sq, off);
    const float rs = rsqrtf(sq * (1.f / 256.f) + 1e-5f);
    float4 o;
    o.x = (v[0] - mu) * rs * g[lane * 4 + 0] + be[lane * 4 + 0];
    o.y = (v[1] - mu) * rs * g[lane * 4 + 1] + be[lane * 4 + 1];
    o.z = (v[2] - mu) * rs * g[lane * 4 + 2] + be[lane * 4 + 2];
    o.w = (v[3] - mu) * rs * g[lane * 4 + 3] + be[lane * 4 + 3];
    *(float4*)(out + row * 256 + lane * 4) = o;
}

// ---------------- launch ----------------
extern "C" void kernel_launch(void* const* d_in, const int* in_sizes, int n_in,
                              void* d_out, int out_size, void* d_ws, size_t ws_size,
                              hipStream_t stream) {
    const float* src = (const float*)d_in[0];
    const float* sph = (const float*)d_in[1];
    const float* Wq  = (const float*)d_in[2];
    const float* bq  = (const float*)d_in[3];
    const float* Wk  = (const float*)d_in[4];
    const float* bk  = (const float*)d_in[5];
    const float* Wv  = (const float*)d_in[6];
    const float* bv  = (const float*)d_in[7];
    const float* Wo  = (const float*)d_in[8];
    const float* bo  = (const float*)d_in[9];
    const float* W1  = (const float*)d_in[10];
    const float* b1  = (const float*)d_in[11];
    const float* W2  = (const float*)d_in[12];
    const float* b2  = (const float*)d_in[13];
    const float* g1  = (const float*)d_in[14];
    const float* be1 = (const float*)d_in[15];
    const float* g2  = (const float*)d_in[16];
    const float* be2 = (const float*)d_in[17];

    char* ws = (char*)d_ws;
    float* X = (float*)d_out;                               // fp32 activations in d_out
    unsigned short* QKV = (unsigned short*)(ws + 0);        // 16384 x 768 bf16 (25.2MB)
    unsigned short* CTX = (unsigned short*)(ws + 25165824); // 16384 x 256
    unsigned short* T2  = (unsigned short*)(ws + 33554432);
    unsigned short* H   = QKV;                              // 16384x1024 bf16 reuses QKV+CTX
    unsigned short* WtQKV = (unsigned short*)(ws + 41943040); // 5 x 768 x 256
    unsigned short* WtO   = (unsigned short*)(ws + 43909120); // 5 x 256 x 256
    unsigned short* Wt1   = (unsigned short*)(ws + 44564480); // 5 x 1024 x 256
    unsigned short* Wt2   = (unsigned short*)(ws + 47185920); // 5 x 256 x 1024
    unsigned short* SPHB  = (unsigned short*)(ws + 50331648); // 8x2048x2048 bf16 (67MB)
    const int use_b16 = (ws_size >= (size_t)117440512);

    const dim3 tb(32, 8);
    transcvt_k<<<dim3(8, 8, 5),  tb, 0, stream>>>(Wq, WtQKV,          256, 256, 65536, 196608);
    transcvt_k<<<dim3(8, 8, 5),  tb, 0, stream>>>(Wk, WtQKV + 65536,  256, 256, 65536, 196608);
    transcvt_k<<<dim3(8, 8, 5),  tb, 0, stream>>>(Wv, WtQKV + 131072, 256, 256, 65536, 196608);
    transcvt_k<<<dim3(8, 8, 5),  tb, 0, stream>>>(Wo, WtO,            256, 256, 65536, 65536);
    transcvt_k<<<dim3(32, 8, 5), tb, 0, stream>>>(W1, Wt1,            256, 1024, 262144, 262144);
    transcvt_k<<<dim3(8, 32, 5), tb, 0, stream>>>(W2, Wt2,            1024, 256, 262144, 262144);
    if (use_b16) sph_cvt<<<16384, 256, 0, stream>>>(sph, SPHB);

    hipMemcpyAsync(X, src, 16777216, hipMemcpyDeviceToDevice, stream);

    const int M = 16384;
    for (int lyr = 0; lyr < 5; ++lyr) {
        gemm_bias_kernel<1, 1><<<dim3(12, 256), 256, 0, stream>>>(
            X, WtQKV + lyr * 196608, bq + lyr * 256, bk + lyr * 256, bv + lyr * 256,
            QKV, M, 768, 256, 0);
        if (use_b16)
            attn_mfma<1><<<2048, 256, 0, stream>>>(QKV, QKV + 256, QKV + 512, sph, SPHB, CTX);
        else
            attn_mfma<0><<<2048, 256, 0, stream>>>(QKV, QKV + 256, QKV + 512, sph, SPHB, CTX);
        gemm_bias_kernel<0, 0><<<dim3(4, 256), 256, 0, stream>>>(
            CTX, WtO + lyr * 65536, bo + lyr * 256, nullptr, nullptr, T2, M, 256, 256, 0);
        add_ln_kernel<<<4096, 256, 0, stream>>>(X, T2, g1 + lyr * 256, be1 + lyr * 256, X);
        gemm_bias_kernel<1, 0><<<dim3(16, 256), 256, 0, stream>>>(
            X, Wt1 + lyr * 262144, b1 + lyr * 1024, nullptr, nullptr, H, M, 1024, 256, 1);
        gemm_bias_kernel<0, 0><<<dim3(4, 256), 256, 0, stream>>>(
            H, Wt2 + lyr * 262144, b2 + lyr * 256, nullptr, nullptr, T2, M, 256, 1024, 0);
        add_ln_kernel<<<4096, 256, 0, stream>>>(X, T2, g2 + lyr * 256, be2 + lyr * 256, X);
    }
}

// Round 3
// 1540.071 us; speedup vs baseline: 1.1597x; 1.1597x over previous
//
#include <hip/hip_runtime.h>
#include <cstdint>

// ---------------- bf16 helpers ----------------
__device__ __forceinline__ float b2f(unsigned short u) {
    unsigned int t = ((unsigned int)u) << 16;
    float f;
    __builtin_memcpy(&f, &t, 4);
    return f;
}
__device__ __forceinline__ unsigned short f2b(float f) {
    unsigned int u;
    __builtin_memcpy(&u, &f, 4);
    unsigned int r = (u + 0x7FFFu + ((u >> 16) & 1u)) >> 16;
    return (unsigned short)r;
}
__device__ __forceinline__ float2 bpair(unsigned int u) {
    float2 r;
    unsigned int lo = u << 16;
    unsigned int hi = u & 0xFFFF0000u;
    __builtin_memcpy(&r.x, &lo, 4);
    __builtin_memcpy(&r.y, &hi, 4);
    return r;
}

typedef __attribute__((ext_vector_type(8))) short bf16x8;
typedef __attribute__((ext_vector_type(4))) float f32x4;

#define LOG2E 1.4426950408889634f
#define SC2   0.2550348595f   /* (1/sqrt(32)) * log2(e) */

// ---------------- weight transpose + fp32->bf16 convert (once per call) ----------------
__global__ void transcvt_k(const float* __restrict__ in,
                           unsigned short* __restrict__ out, int R, int C,
                           int in_z, int out_z) {
    __shared__ float tile[32][33];
    in += (size_t)blockIdx.z * in_z;
    out += (size_t)blockIdx.z * out_z;
    const int c0 = blockIdx.x * 32, r0 = blockIdx.y * 32;
    const int tx = threadIdx.x, ty = threadIdx.y;
#pragma unroll
    for (int i = 0; i < 32; i += 8)
        tile[ty + i][tx] = in[(size_t)(r0 + ty + i) * C + c0 + tx];
    __syncthreads();
#pragma unroll
    for (int i = 0; i < 32; i += 8)
        out[(size_t)(c0 + ty + i) * R + r0 + tx] = f2b(tile[tx][ty + i]);
}

// ---------------- sph -> bf16 * log2e (once per call) ----------------
__global__ __launch_bounds__(256) void sph_cvt(const float* __restrict__ in,
                                               unsigned short* __restrict__ out) {
    const size_t idx = (size_t)blockIdx.x * 256 + threadIdx.x;
    const float4 a = ((const float4*)in)[idx * 2];
    const float4 b = ((const float4*)in)[idx * 2 + 1];
    uint4 o;
    o.x = (unsigned)f2b(a.x * LOG2E) | ((unsigned)f2b(a.y * LOG2E) << 16);
    o.y = (unsigned)f2b(a.z * LOG2E) | ((unsigned)f2b(a.w * LOG2E) << 16);
    o.z = (unsigned)f2b(b.x * LOG2E) | ((unsigned)f2b(b.y * LOG2E) << 16);
    o.w = (unsigned)f2b(b.z * LOG2E) | ((unsigned)f2b(b.w * LOG2E) << 16);
    ((uint4*)out)[idx] = o;
}

// ---------------- fp32 -> bf16 convert (initial XB) ----------------
__global__ __launch_bounds__(256) void cvt_bf16_k(const float* __restrict__ in,
                                                  unsigned short* __restrict__ out) {
    const size_t idx = (size_t)blockIdx.x * 256 + threadIdx.x;
    const float4 a = ((const float4*)in)[idx * 2];
    const float4 b = ((const float4*)in)[idx * 2 + 1];
    uint4 o;
    o.x = (unsigned)f2b(a.x) | ((unsigned)f2b(a.y) << 16);
    o.y = (unsigned)f2b(a.z) | ((unsigned)f2b(a.w) << 16);
    o.z = (unsigned)f2b(b.x) | ((unsigned)f2b(b.y) << 16);
    o.w = (unsigned)f2b(b.z) | ((unsigned)f2b(b.w) << 16);
    ((uint4*)out)[idx] = o;
}

// ---------------- old 64x64 GEMM (fallback path) ----------------
template <int AF32, int QKVB>
__global__ __launch_bounds__(256) void gemm_bias_kernel(
    const void* __restrict__ Ap, const unsigned short* __restrict__ Wt,
    const float* __restrict__ biasQ, const float* __restrict__ biasK,
    const float* __restrict__ biasV, unsigned short* __restrict__ C,
    int M, int N, int K, int do_gelu) {
    __shared__ unsigned short As[64 * 40];
    __shared__ unsigned short Bs[64 * 40];
    const int tid = threadIdx.x;
    const int lane = tid & 63, wid = tid >> 6;
    const int m0 = blockIdx.y * 64, n0 = blockIdx.x * 64;
    const int wm = (wid >> 1) * 32, wn = (wid & 1) * 32;
    const int quad = lane >> 4, mrow = lane & 15;
    f32x4 acc[2][2] = {};
    const int arow = tid >> 2, ak = (tid & 3) << 3;
    const unsigned short* Bg = Wt + (size_t)(n0 + arow) * K + ak;
    const float* Agf = (const float*)Ap + (size_t)(m0 + arow) * K + ak;
    const unsigned short* Agb = (const unsigned short*)Ap + (size_t)(m0 + arow) * K + ak;

    typedef __attribute__((ext_vector_type(8))) short short8;
    for (int kb = 0; kb < K; kb += 32) {
        if (AF32) {
            float4 f0 = *(const float4*)(Agf + kb);
            float4 f1 = *(const float4*)(Agf + kb + 4);
            short8 t;
            t[0] = (short)f2b(f0.x); t[1] = (short)f2b(f0.y);
            t[2] = (short)f2b(f0.z); t[3] = (short)f2b(f0.w);
            t[4] = (short)f2b(f1.x); t[5] = (short)f2b(f1.y);
            t[6] = (short)f2b(f1.z); t[7] = (short)f2b(f1.w);
            *(short8*)&As[arow * 40 + ak] = t;
        } else {
            *(uint4*)&As[arow * 40 + ak] = *(const uint4*)(Agb + kb);
        }
        *(uint4*)&Bs[arow * 40 + ak] = *(const uint4*)(Bg + kb);
        __syncthreads();
        bf16x8 a0 = *(const bf16x8*)&As[(wm + mrow) * 40 + quad * 8];
        bf16x8 a1 = *(const bf16x8*)&As[(wm + 16 + mrow) * 40 + quad * 8];
        bf16x8 b0 = *(const bf16x8*)&Bs[(wn + mrow) * 40 + quad * 8];
        bf16x8 b1 = *(const bf16x8*)&Bs[(wn + 16 + mrow) * 40 + quad * 8];
        acc[0][0] = __builtin_amdgcn_mfma_f32_16x16x32_bf16(a0, b0, acc[0][0], 0, 0, 0);
        acc[0][1] = __builtin_amdgcn_mfma_f32_16x16x32_bf16(a0, b1, acc[0][1], 0, 0, 0);
        acc[1][0] = __builtin_amdgcn_mfma_f32_16x16x32_bf16(a1, b0, acc[1][0], 0, 0, 0);
        acc[1][1] = __builtin_amdgcn_mfma_f32_16x16x32_bf16(a1, b1, acc[1][1], 0, 0, 0);
        __syncthreads();
    }
    const float* bp;
    if (QKVB) {
        const int bsel = n0 >> 8;
        bp = bsel == 0 ? biasQ : (bsel == 1 ? biasK : biasV);
    } else {
        bp = biasQ;
    }
#pragma unroll
    for (int i = 0; i < 2; i++)
#pragma unroll
        for (int j = 0; j < 2; j++) {
            const int col = n0 + wn + j * 16 + mrow;
            const float bv = QKVB ? bp[col & 255] : bp[col];
#pragma unroll
            for (int r = 0; r < 4; r++) {
                const int row = m0 + wm + i * 16 + quad * 4 + r;
                float v = acc[i][j][r] + bv;
                if (do_gelu) v = 0.5f * v * (1.0f + erff(v * 0.70710678118654752f));
                C[(size_t)row * N + col] = f2b(v);
            }
        }
}

// ---------------- 128-row tile GEMM, bf16 A, TN = 128 or 64 ----------------
// 4 waves as 2x2; wave tile 64 x (TN/2); acc 4 x (TN/32). BK=32, LDS stride 40
// (2-way bank aliasing = free). Global loads issued BEFORE the barrier so HBM
// latency hides under the previous tile's MFMAs (issue-early/write-late).
template <int TN, int QKVB>
__global__ __launch_bounds__(256) void gemm128_kernel(
    const unsigned short* __restrict__ A, const unsigned short* __restrict__ Wt,
    const float* __restrict__ biasQ, const float* __restrict__ biasK,
    const float* __restrict__ biasV, unsigned short* __restrict__ C,
    int M, int N, int K, int do_gelu) {
    constexpr int JN = TN / 32;  // B frags per wave
    __shared__ unsigned short As[128 * 40];
    __shared__ unsigned short Bs[TN * 40];
    const int tid = threadIdx.x;
    const int lane = tid & 63, wid = tid >> 6;
    const int m0 = blockIdx.y * 128, n0 = blockIdx.x * TN;
    const int wm = (wid >> 1) * 64, wn = (wid & 1) * (TN / 2);
    const int quad = lane >> 4, mrow = lane & 15;
    f32x4 acc[4][JN] = {};
    const int srow = tid >> 2, scol = (tid & 3) << 3;  // 64 rows x 32 cols per pass
    const unsigned short* Ag = A + (size_t)(m0 + srow) * K + scol;
    const unsigned short* Bg = Wt + (size_t)(n0 + srow) * K + scol;

    for (int kb = 0; kb < K; kb += 32) {
        // issue global loads early (previous tile still being consumed)
        const uint4 a0 = *(const uint4*)(Ag + kb);
        const uint4 a1 = *(const uint4*)(Ag + (size_t)64 * K + kb);
        const uint4 b0 = *(const uint4*)(Bg + kb);
        uint4 b1 = {};
        if constexpr (TN == 128) b1 = *(const uint4*)(Bg + (size_t)64 * K + kb);
        __syncthreads();
        *(uint4*)&As[srow * 40 + scol] = a0;
        *(uint4*)&As[(srow + 64) * 40 + scol] = a1;
        *(uint4*)&Bs[srow * 40 + scol] = b0;
        if constexpr (TN == 128) *(uint4*)&Bs[(srow + 64) * 40 + scol] = b1;
        __syncthreads();
        bf16x8 af[4], bfr[JN];
#pragma unroll
        for (int i = 0; i < 4; i++)
            af[i] = *(const bf16x8*)&As[(wm + i * 16 + mrow) * 40 + quad * 8];
#pragma unroll
        for (int j = 0; j < JN; j++)
            bfr[j] = *(const bf16x8*)&Bs[(wn + j * 16 + mrow) * 40 + quad * 8];
#pragma unroll
        for (int i = 0; i < 4; i++)
#pragma unroll
            for (int j = 0; j < JN; j++)
                acc[i][j] = __builtin_amdgcn_mfma_f32_16x16x32_bf16(af[i], bfr[j], acc[i][j], 0, 0, 0);
    }

    const float* bp;
    if (QKVB) {
        const int bsel = n0 >> 8;
        bp = bsel == 0 ? biasQ : (bsel == 1 ? biasK : biasV);
    } else {
        bp = biasQ;
    }
#pragma unroll
    for (int i = 0; i < 4; i++)
#pragma unroll
        for (int j = 0; j < JN; j++) {
            const int col = n0 + wn + j * 16 + mrow;
            const float bv = QKVB ? bp[col & 255] : bp[col];
#pragma unroll
            for (int r = 0; r < 4; r++) {
                const int row = m0 + wm + i * 16 + quad * 4 + r;
                float v = acc[i][j][r] + bv;
                if (do_gelu) v = 0.5f * v * (1.0f + erff(v * 0.70710678118654752f));
                C[(size_t)row * N + col] = f2b(v);
            }
        }
}

// ---------------- attention: flash-style MFMA, no-max exp2 softmax ----------------
// (round-0 version — verified 156 us)
template <int SPHB16>
__global__ __launch_bounds__(256) void attn_mfma(
    const unsigned short* __restrict__ Qb, const unsigned short* __restrict__ Kb,
    const unsigned short* __restrict__ Vb, const float* __restrict__ sphf,
    const unsigned short* __restrict__ sphb, unsigned short* __restrict__ Ctx) {
    __shared__ unsigned short Ks[64 * 40];
    __shared__ unsigned short Vt[32 * 72];
    __shared__ unsigned short Ps[4][16 * 72];

    const int tid = threadIdx.x, lane = tid & 63, wid = tid >> 6;
    const int quad = lane >> 4, lq = lane & 15;
    const int bid = blockIdx.x;
    const int h = bid >> 8, b = (bid >> 5) & 7, qt = bid & 31;
    const int q0 = qt * 64;
    const size_t bS = (size_t)b * 2048;

    const int skey = tid >> 2, sdg = (tid & 3) << 3;
    const unsigned short* kgp = Kb + (bS + skey) * 768 + h * 32 + sdg;
    const int vkp = tid & 31, vdg = (tid >> 5) << 2;
    const unsigned short* vgp = Vb + (bS + 2 * vkp) * 768 + h * 32 + vdg;

    const bf16x8 qf = *(const bf16x8*)(Qb + (bS + q0 + wid * 16 + lq) * 768 + h * 32 + quad * 8);

    const size_t sprow = ((size_t)b * 2048 + q0 + wid * 16 + quad * 4) * 2048 + lq;
    const float* spf = sphf + sprow;
    const unsigned short* spb = sphb + sprow;

    float l_r[4] = {0.f, 0.f, 0.f, 0.f};
    f32x4 o0 = {}, o1 = {};

    for (int kt = 0; kt < 32; ++kt) {
        const int k0 = kt * 64;
        __syncthreads();                        // protect Ks/Vt reuse
        *(uint4*)&Ks[skey * 40 + sdg] = *(const uint4*)(kgp + (size_t)k0 * 768);
        {
            uint2 va = *(const uint2*)(vgp + (size_t)k0 * 768);
            uint2 vb2 = *(const uint2*)(vgp + (size_t)k0 * 768 + 768);
            *(unsigned int*)&Vt[(vdg + 0) * 72 + 2 * vkp] = (va.x & 0xFFFFu) | (vb2.x << 16);
            *(unsigned int*)&Vt[(vdg + 1) * 72 + 2 * vkp] = (va.x >> 16) | (vb2.x & 0xFFFF0000u);
            *(unsigned int*)&Vt[(vdg + 2) * 72 + 2 * vkp] = (va.y & 0xFFFFu) | (vb2.y << 16);
            *(unsigned int*)&Vt[(vdg + 3) * 72 + 2 * vkp] = (va.y >> 16) | (vb2.y & 0xFFFF0000u);
        }
        __syncthreads();

        const f32x4 zf = {};
        f32x4 sa0 = __builtin_amdgcn_mfma_f32_16x16x32_bf16(
            qf, *(const bf16x8*)&Ks[(0  + lq) * 40 + quad * 8], zf, 0, 0, 0);
        f32x4 sa1 = __builtin_amdgcn_mfma_f32_16x16x32_bf16(
            qf, *(const bf16x8*)&Ks[(16 + lq) * 40 + quad * 8], zf, 0, 0, 0);
        f32x4 sa2 = __builtin_amdgcn_mfma_f32_16x16x32_bf16(
            qf, *(const bf16x8*)&Ks[(32 + lq) * 40 + quad * 8], zf, 0, 0, 0);
        f32x4 sa3 = __builtin_amdgcn_mfma_f32_16x16x32_bf16(
            qf, *(const bf16x8*)&Ks[(48 + lq) * 40 + quad * 8], zf, 0, 0, 0);

#pragma unroll
        for (int r = 0; r < 4; ++r) {
            float sb0, sb1, sb2, sb3;
            if (SPHB16) {
                const unsigned short* spr = spb + (size_t)r * 2048 + k0;
                sb0 = b2f(spr[0]);  sb1 = b2f(spr[16]);
                sb2 = b2f(spr[32]); sb3 = b2f(spr[48]);
            } else {
                const float* spr = spf + (size_t)r * 2048 + k0;
                sb0 = spr[0]  * LOG2E; sb1 = spr[16] * LOG2E;
                sb2 = spr[32] * LOG2E; sb3 = spr[48] * LOG2E;
            }
            const float p0 = __builtin_amdgcn_exp2f(fmaf(sa0[r], SC2, sb0));
            const float p1 = __builtin_amdgcn_exp2f(fmaf(sa1[r], SC2, sb1));
            const float p2 = __builtin_amdgcn_exp2f(fmaf(sa2[r], SC2, sb2));
            const float p3 = __builtin_amdgcn_exp2f(fmaf(sa3[r], SC2, sb3));
            l_r[r] += (p0 + p1) + (p2 + p3);
            unsigned short* pw = &Ps[wid][(quad * 4 + r) * 72 + lq];
            pw[0]  = f2b(p0);
            pw[16] = f2b(p1);
            pw[32] = f2b(p2);
            pw[48] = f2b(p3);
        }

#pragma unroll
        for (int k2 = 0; k2 < 2; ++k2) {
            bf16x8 pf = *(const bf16x8*)&Ps[wid][lq * 72 + k2 * 32 + quad * 8];
            o0 = __builtin_amdgcn_mfma_f32_16x16x32_bf16(
                pf, *(const bf16x8*)&Vt[(0  + lq) * 72 + k2 * 32 + quad * 8], o0, 0, 0, 0);
            o1 = __builtin_amdgcn_mfma_f32_16x16x32_bf16(
                pf, *(const bf16x8*)&Vt[(16 + lq) * 72 + k2 * 32 + quad * 8], o1, 0, 0, 0);
        }
    }

    unsigned short* op = Ctx + (bS + q0 + wid * 16 + quad * 4) * 256 + h * 32;
#pragma unroll
    for (int r = 0; r < 4; ++r) {
        float l = l_r[r];
        l += __shfl_xor(l, 1);
        l += __shfl_xor(l, 2);
        l += __shfl_xor(l, 4);
        l += __shfl_xor(l, 8);
        const float inv = 1.f / l;
        op[r * 256 + lq]      = f2b(o0[r] * inv);
        op[r * 256 + 16 + lq] = f2b(o1[r] * inv);
    }
}

// ---------------- fused residual + LayerNorm (fp32 stream + optional bf16 copy) ----------------
__global__ __launch_bounds__(256) void add_ln_kernel(
    const float* __restrict__ x, const unsigned short* __restrict__ r,
    const float* __restrict__ g, const float* __restrict__ be,
    float* __restrict__ out, unsigned short* __restrict__ xb) {
    const int lane = threadIdx.x & 63, wid = threadIdx.x >> 6;
    const size_t row = (size_t)blockIdx.x * 4 + wid;
    float4 xv = *(const float4*)(x + row * 256 + lane * 4);
    uint2 ru = *(const uint2*)(r + row * 256 + lane * 4);
    float2 ra = bpair(ru.x), rb = bpair(ru.y);
    float v[4] = {xv.x + ra.x, xv.y + ra.y, xv.z + rb.x, xv.w + rb.y};
    float sum = v[0] + v[1] + v[2] + v[3];
#pragma unroll
    for (int off = 32; off; off >>= 1) sum += __shfl_xor(sum, off);
    const float mu = sum * (1.f / 256.f);
    float sq = 0.f;
#pragma unroll
    for (int i = 0; i < 4; i++) { float d = v[i] - mu; sq += d * d; }
#pragma unroll
    for (int off = 32; off; off >>= 1) sq += __shfl_xor(sq, off);
    const float rs = rsqrtf(sq * (1.f / 256.f) + 1e-5f);
    float4 o;
    o.x = (v[0] - mu) * rs * g[lane * 4 + 0] + be[lane * 4 + 0];
    o.y = (v[1] - mu) * rs * g[lane * 4 + 1] + be[lane * 4 + 1];
    o.z = (v[2] - mu) * rs * g[lane * 4 + 2] + be[lane * 4 + 2];
    o.w = (v[3] - mu) * rs * g[lane * 4 + 3] + be[lane * 4 + 3];
    *(float4*)(out + row * 256 + lane * 4) = o;
    if (xb) {
        uint2 p;
        p.x = (unsigned)f2b(o.x) | ((unsigned)f2b(o.y) << 16);
        p.y = (unsigned)f2b(o.z) | ((unsigned)f2b(o.w) << 16);
        *(uint2*)(xb + row * 256 + lane * 4) = p;
    }
}

// ---------------- launch ----------------
extern "C" void kernel_launch(void* const* d_in, const int* in_sizes, int n_in,
                              void* d_out, int out_size, void* d_ws, size_t ws_size,
                              hipStream_t stream) {
    const float* src = (const float*)d_in[0];
    const float* sph = (const float*)d_in[1];
    const float* Wq  = (const float*)d_in[2];
    const float* bq  = (const float*)d_in[3];
    const float* Wk  = (const float*)d_in[4];
    const float* bk  = (const float*)d_in[5];
    const float* Wv  = (const float*)d_in[6];
    const float* bv  = (const float*)d_in[7];
    const float* Wo  = (const float*)d_in[8];
    const float* bo  = (const float*)d_in[9];
    const float* W1  = (const float*)d_in[10];
    const float* b1  = (const float*)d_in[11];
    const float* W2  = (const float*)d_in[12];
    const float* b2  = (const float*)d_in[13];
    const float* g1  = (const float*)d_in[14];
    const float* be1 = (const float*)d_in[15];
    const float* g2  = (const float*)d_in[16];
    const float* be2 = (const float*)d_in[17];

    char* ws = (char*)d_ws;
    float* X = (float*)d_out;                               // fp32 activations in d_out
    unsigned short* QKV = (unsigned short*)(ws + 0);        // 16384 x 768 bf16 (25.2MB)
    unsigned short* CTX = (unsigned short*)(ws + 25165824); // 16384 x 256
    unsigned short* T2  = (unsigned short*)(ws + 33554432);
    unsigned short* H   = QKV;                              // 16384x1024 bf16 reuses QKV+CTX
    unsigned short* WtQKV = (unsigned short*)(ws + 41943040); // 5 x 768 x 256
    unsigned short* WtO   = (unsigned short*)(ws + 43909120); // 5 x 256 x 256
    unsigned short* Wt1   = (unsigned short*)(ws + 44564480); // 5 x 1024 x 256
    unsigned short* Wt2   = (unsigned short*)(ws + 47185920); // 5 x 256 x 1024
    unsigned short* SPHB  = (unsigned short*)(ws + 50331648); // 8x2048x2048 bf16 (67MB)
    unsigned short* XB    = (unsigned short*)(ws + 117440512); // 16384 x 256 bf16 (8MB)
    const int use_b16 = (ws_size >= (size_t)117440512);
    const int use_xb  = (ws_size >= (size_t)125829120);

    const dim3 tb(32, 8);
    transcvt_k<<<dim3(8, 8, 5),  tb, 0, stream>>>(Wq, WtQKV,          256, 256, 65536, 196608);
    transcvt_k<<<dim3(8, 8, 5),  tb, 0, stream>>>(Wk, WtQKV + 65536,  256, 256, 65536, 196608);
    transcvt_k<<<dim3(8, 8, 5),  tb, 0, stream>>>(Wv, WtQKV + 131072, 256, 256, 65536, 196608);
    transcvt_k<<<dim3(8, 8, 5),  tb, 0, stream>>>(Wo, WtO,            256, 256, 65536, 65536);
    transcvt_k<<<dim3(32, 8, 5), tb, 0, stream>>>(W1, Wt1,            256, 1024, 262144, 262144);
    transcvt_k<<<dim3(8, 32, 5), tb, 0, stream>>>(W2, Wt2,            1024, 256, 262144, 262144);
    if (use_b16) sph_cvt<<<16384, 256, 0, stream>>>(sph, SPHB);
    if (use_xb)  cvt_bf16_k<<<2048, 256, 0, stream>>>(src, XB);

    hipMemcpyAsync(X, src, 16777216, hipMemcpyDeviceToDevice, stream);

    const int M = 16384;
    unsigned short* xb_arg = use_xb ? XB : nullptr;
    for (int lyr = 0; lyr < 5; ++lyr) {
        if (use_xb) {
            gemm128_kernel<128, 1><<<dim3(6, 128), 256, 0, stream>>>(
                XB, WtQKV + lyr * 196608, bq + lyr * 256, bk + lyr * 256, bv + lyr * 256,
                QKV, M, 768, 256, 0);
        } else {
            gemm_bias_kernel<1, 1><<<dim3(12, 256), 256, 0, stream>>>(
                X, WtQKV + lyr * 196608, bq + lyr * 256, bk + lyr * 256, bv + lyr * 256,
                QKV, M, 768, 256, 0);
        }
        if (use_b16)
            attn_mfma<1><<<2048, 256, 0, stream>>>(QKV, QKV + 256, QKV + 512, sph, SPHB, CTX);
        else
            attn_mfma<0><<<2048, 256, 0, stream>>>(QKV, QKV + 256, QKV + 512, sph, SPHB, CTX);
        if (use_xb) {
            gemm128_kernel<64, 0><<<dim3(4, 128), 256, 0, stream>>>(
                CTX, WtO + lyr * 65536, bo + lyr * 256, nullptr, nullptr, T2, M, 256, 256, 0);
        } else {
            gemm_bias_kernel<0, 0><<<dim3(4, 256), 256, 0, stream>>>(
                CTX, WtO + lyr * 65536, bo + lyr * 256, nullptr, nullptr, T2, M, 256, 256, 0);
        }
        add_ln_kernel<<<4096, 256, 0, stream>>>(X, T2, g1 + lyr * 256, be1 + lyr * 256, X, xb_arg);
        if (use_xb) {
            gemm128_kernel<128, 0><<<dim3(8, 128), 256, 0, stream>>>(
                XB, Wt1 + lyr * 262144, b1 + lyr * 1024, nullptr, nullptr, H, M, 1024, 256, 1);
            gemm128_kernel<64, 0><<<dim3(4, 128), 256, 0, stream>>>(
                H, Wt2 + lyr * 262144, b2 + lyr * 256, nullptr, nullptr, T2, M, 256, 1024, 0);
        } else {
            gemm_bias_kernel<1, 0><<<dim3(16, 256), 256, 0, stream>>>(
                X, Wt1 + lyr * 262144, b1 + lyr * 1024, nullptr, nullptr, H, M, 1024, 256, 1);
            gemm_bias_kernel<0, 0><<<dim3(4, 256), 256, 0, stream>>>(
                H, Wt2 + lyr * 262144, b2 + lyr * 256, nullptr, nullptr, T2, M, 256, 1024, 0);
        }
        add_ln_kernel<<<4096, 256, 0, stream>>>(X, T2, g2 + lyr * 256, be2 + lyr * 256, X, xb_arg);
    }
}

// Round 4
// 1493.094 us; speedup vs baseline: 1.1962x; 1.0315x over previous
//
#include <hip/hip_runtime.h>
#include <cstdint>

// ---------------- bf16 helpers ----------------
__device__ __forceinline__ float b2f(unsigned short u) {
    unsigned int t = ((unsigned int)u) << 16;
    float f;
    __builtin_memcpy(&f, &t, 4);
    return f;
}
__device__ __forceinline__ unsigned short f2b(float f) {
    unsigned int u;
    __builtin_memcpy(&u, &f, 4);
    unsigned int r = (u + 0x7FFFu + ((u >> 16) & 1u)) >> 16;
    return (unsigned short)r;
}
__device__ __forceinline__ float2 bpair(unsigned int u) {
    float2 r;
    unsigned int lo = u << 16;
    unsigned int hi = u & 0xFFFF0000u;
    __builtin_memcpy(&r.x, &lo, 4);
    __builtin_memcpy(&r.y, &hi, 4);
    return r;
}

typedef __attribute__((ext_vector_type(8))) short bf16x8;
typedef __attribute__((ext_vector_type(4))) float f32x4;

#define LOG2E 1.4426950408889634f
#define SC2   0.2550348595f   /* (1/sqrt(32)) * log2(e) */

// 16-byte global -> LDS async copy (LDS dest must be linear: base + lane*16)
__device__ __forceinline__ void gload16(const void* g, void* l) {
    __builtin_amdgcn_global_load_lds(
        (const __attribute__((address_space(1))) unsigned int*)g,
        (__attribute__((address_space(3))) unsigned int*)l, 16, 0, 0);
}

// ---------------- weight transpose + fp32->bf16 convert (once per call) ----------------
__global__ void transcvt_k(const float* __restrict__ in,
                           unsigned short* __restrict__ out, int R, int C,
                           int in_z, int out_z) {
    __shared__ float tile[32][33];
    in += (size_t)blockIdx.z * in_z;
    out += (size_t)blockIdx.z * out_z;
    const int c0 = blockIdx.x * 32, r0 = blockIdx.y * 32;
    const int tx = threadIdx.x, ty = threadIdx.y;
#pragma unroll
    for (int i = 0; i < 32; i += 8)
        tile[ty + i][tx] = in[(size_t)(r0 + ty + i) * C + c0 + tx];
    __syncthreads();
#pragma unroll
    for (int i = 0; i < 32; i += 8)
        out[(size_t)(c0 + ty + i) * R + r0 + tx] = f2b(tile[tx][ty + i]);
}

// ---------------- sph -> bf16 * log2e (once per call) ----------------
__global__ __launch_bounds__(256) void sph_cvt(const float* __restrict__ in,
                                               unsigned short* __restrict__ out) {
    const size_t idx = (size_t)blockIdx.x * 256 + threadIdx.x;
    const float4 a = ((const float4*)in)[idx * 2];
    const float4 b = ((const float4*)in)[idx * 2 + 1];
    uint4 o;
    o.x = (unsigned)f2b(a.x * LOG2E) | ((unsigned)f2b(a.y * LOG2E) << 16);
    o.y = (unsigned)f2b(a.z * LOG2E) | ((unsigned)f2b(a.w * LOG2E) << 16);
    o.z = (unsigned)f2b(b.x * LOG2E) | ((unsigned)f2b(b.y * LOG2E) << 16);
    o.w = (unsigned)f2b(b.z * LOG2E) | ((unsigned)f2b(b.w * LOG2E) << 16);
    ((uint4*)out)[idx] = o;
}

// ---------------- fp32 -> bf16 convert (initial XB) ----------------
__global__ __launch_bounds__(256) void cvt_bf16_k(const float* __restrict__ in,
                                                  unsigned short* __restrict__ out) {
    const size_t idx = (size_t)blockIdx.x * 256 + threadIdx.x;
    const float4 a = ((const float4*)in)[idx * 2];
    const float4 b = ((const float4*)in)[idx * 2 + 1];
    uint4 o;
    o.x = (unsigned)f2b(a.x) | ((unsigned)f2b(a.y) << 16);
    o.y = (unsigned)f2b(a.z) | ((unsigned)f2b(a.w) << 16);
    o.z = (unsigned)f2b(b.x) | ((unsigned)f2b(b.y) << 16);
    o.w = (unsigned)f2b(b.z) | ((unsigned)f2b(b.w) << 16);
    ((uint4*)out)[idx] = o;
}

// ---------------- GEMM via global_load_lds: C[M,N] = A[M,K] @ Wt[N,K]^T ----------------
// Tile 128 x TN, BK=64. 4 waves 2x2 (wave tile 64 x TN/2). Staging: linear LDS
// (row-major [rows][64] shorts) via global_load_lds width 16; global source
// column is pre-swizzled by slot^ (row&7) so fragment reads (which apply the
// same XOR) are bank-conflict-free at the 128B row stride (both-sides rule).
template <int TN, int QKVB>
__global__ __launch_bounds__(256) void gemm_gl_kernel(
    const unsigned short* __restrict__ A, const unsigned short* __restrict__ Wt,
    const float* __restrict__ biasQ, const float* __restrict__ biasK,
    const float* __restrict__ biasV, unsigned short* __restrict__ C,
    int M, int N, int K, int do_gelu) {
    constexpr int JN = TN / 32;          // B frags per wave (per k-half)
    constexpr int NCH = 16 + TN / 8;     // 1KB staging chunks: 16 A + TN/8 B
    __shared__ unsigned short As[128 * 64];
    __shared__ unsigned short Bs[TN * 64];
    const int tid = threadIdx.x;
    const int lane = tid & 63, wid = tid >> 6;
    const int m0 = blockIdx.y * 128, n0 = blockIdx.x * TN;
    const int wm = (wid >> 1) * 64, wn = (wid & 1) * (TN / 2);
    const int quad = lane >> 4, mrow = lane & 15;
    const int lrow = lane >> 3, lslot = lane & 7;
    f32x4 acc[4][JN] = {};

    for (int kb = 0; kb < K; kb += 64) {
#pragma unroll
        for (int cc = 0; cc < NCH / 4; ++cc) {
            const int c = wid * (NCH / 4) + cc;    // wave-uniform chunk id
            if (c < 16) {
                const int row = c * 8 + lrow;
                const int gcol = ((lslot ^ (row & 7)) << 3) + kb;
                gload16(A + (size_t)(m0 + row) * K + gcol, &As[c * 512 + lane * 8]);
            } else {
                const int row = (c - 16) * 8 + lrow;
                const int gcol = ((lslot ^ (row & 7)) << 3) + kb;
                gload16(Wt + (size_t)(n0 + row) * K + gcol, &Bs[(c - 16) * 512 + lane * 8]);
            }
        }
        __syncthreads();   // compiler drains vmcnt(0) here (m97 structure)
#pragma unroll
        for (int h = 0; h < 2; ++h) {
            bf16x8 af[4], bfr[JN];
#pragma unroll
            for (int i = 0; i < 4; i++) {
                const int ar = wm + i * 16 + mrow;
                af[i] = *(const bf16x8*)&As[ar * 64 + (((h * 4 + quad) ^ (ar & 7)) << 3)];
            }
#pragma unroll
            for (int j = 0; j < JN; j++) {
                const int br = wn + j * 16 + mrow;
                bfr[j] = *(const bf16x8*)&Bs[br * 64 + (((h * 4 + quad) ^ (br & 7)) << 3)];
            }
#pragma unroll
            for (int i = 0; i < 4; i++)
#pragma unroll
                for (int j = 0; j < JN; j++)
                    acc[i][j] = __builtin_amdgcn_mfma_f32_16x16x32_bf16(af[i], bfr[j], acc[i][j], 0, 0, 0);
        }
        __syncthreads();
    }

    const float* bp;
    if (QKVB) {
        const int bsel = n0 >> 8;
        bp = bsel == 0 ? biasQ : (bsel == 1 ? biasK : biasV);
    } else {
        bp = biasQ;
    }
#pragma unroll
    for (int i = 0; i < 4; i++)
#pragma unroll
        for (int j = 0; j < JN; j++) {
            const int col = n0 + wn + j * 16 + mrow;
            const float bv = QKVB ? bp[col & 255] : bp[col];
#pragma unroll
            for (int r = 0; r < 4; r++) {
                const int row = m0 + wm + i * 16 + quad * 4 + r;
                float v = acc[i][j][r] + bv;
                if (do_gelu) v = 0.5f * v * (1.0f + erff(v * 0.70710678118654752f));
                C[(size_t)row * N + col] = f2b(v);
            }
        }
}

// ---------------- attention: flash-style MFMA, no-max exp2 softmax ----------------
// (round-0 version — verified 156-158 us)
template <int SPHB16>
__global__ __launch_bounds__(256) void attn_mfma(
    const unsigned short* __restrict__ Qb, const unsigned short* __restrict__ Kb,
    const unsigned short* __restrict__ Vb, const float* __restrict__ sphf,
    const unsigned short* __restrict__ sphb, unsigned short* __restrict__ Ctx) {
    __shared__ unsigned short Ks[64 * 40];
    __shared__ unsigned short Vt[32 * 72];
    __shared__ unsigned short Ps[4][16 * 72];

    const int tid = threadIdx.x, lane = tid & 63, wid = tid >> 6;
    const int quad = lane >> 4, lq = lane & 15;
    const int bid = blockIdx.x;
    const int h = bid >> 8, b = (bid >> 5) & 7, qt = bid & 31;
    const int q0 = qt * 64;
    const size_t bS = (size_t)b * 2048;

    const int skey = tid >> 2, sdg = (tid & 3) << 3;
    const unsigned short* kgp = Kb + (bS + skey) * 768 + h * 32 + sdg;
    const int vkp = tid & 31, vdg = (tid >> 5) << 2;
    const unsigned short* vgp = Vb + (bS + 2 * vkp) * 768 + h * 32 + vdg;

    const bf16x8 qf = *(const bf16x8*)(Qb + (bS + q0 + wid * 16 + lq) * 768 + h * 32 + quad * 8);

    const size_t sprow = ((size_t)b * 2048 + q0 + wid * 16 + quad * 4) * 2048 + lq;
    const float* spf = sphf + sprow;
    const unsigned short* spb = sphb + sprow;

    float l_r[4] = {0.f, 0.f, 0.f, 0.f};
    f32x4 o0 = {}, o1 = {};

    for (int kt = 0; kt < 32; ++kt) {
        const int k0 = kt * 64;
        __syncthreads();                        // protect Ks/Vt reuse
        *(uint4*)&Ks[skey * 40 + sdg] = *(const uint4*)(kgp + (size_t)k0 * 768);
        {
            uint2 va = *(const uint2*)(vgp + (size_t)k0 * 768);
            uint2 vb2 = *(const uint2*)(vgp + (size_t)k0 * 768 + 768);
            *(unsigned int*)&Vt[(vdg + 0) * 72 + 2 * vkp] = (va.x & 0xFFFFu) | (vb2.x << 16);
            *(unsigned int*)&Vt[(vdg + 1) * 72 + 2 * vkp] = (va.x >> 16) | (vb2.x & 0xFFFF0000u);
            *(unsigned int*)&Vt[(vdg + 2) * 72 + 2 * vkp] = (va.y & 0xFFFFu) | (vb2.y << 16);
            *(unsigned int*)&Vt[(vdg + 3) * 72 + 2 * vkp] = (va.y >> 16) | (vb2.y & 0xFFFF0000u);
        }
        __syncthreads();

        const f32x4 zf = {};
        f32x4 sa0 = __builtin_amdgcn_mfma_f32_16x16x32_bf16(
            qf, *(const bf16x8*)&Ks[(0  + lq) * 40 + quad * 8], zf, 0, 0, 0);
        f32x4 sa1 = __builtin_amdgcn_mfma_f32_16x16x32_bf16(
            qf, *(const bf16x8*)&Ks[(16 + lq) * 40 + quad * 8], zf, 0, 0, 0);
        f32x4 sa2 = __builtin_amdgcn_mfma_f32_16x16x32_bf16(
            qf, *(const bf16x8*)&Ks[(32 + lq) * 40 + quad * 8], zf, 0, 0, 0);
        f32x4 sa3 = __builtin_amdgcn_mfma_f32_16x16x32_bf16(
            qf, *(const bf16x8*)&Ks[(48 + lq) * 40 + quad * 8], zf, 0, 0, 0);

#pragma unroll
        for (int r = 0; r < 4; ++r) {
            float sb0, sb1, sb2, sb3;
            if (SPHB16) {
                const unsigned short* spr = spb + (size_t)r * 2048 + k0;
                sb0 = b2f(spr[0]);  sb1 = b2f(spr[16]);
                sb2 = b2f(spr[32]); sb3 = b2f(spr[48]);
            } else {
                const float* spr = spf + (size_t)r * 2048 + k0;
                sb0 = spr[0]  * LOG2E; sb1 = spr[16] * LOG2E;
                sb2 = spr[32] * LOG2E; sb3 = spr[48] * LOG2E;
            }
            const float p0 = __builtin_amdgcn_exp2f(fmaf(sa0[r], SC2, sb0));
            const float p1 = __builtin_amdgcn_exp2f(fmaf(sa1[r], SC2, sb1));
            const float p2 = __builtin_amdgcn_exp2f(fmaf(sa2[r], SC2, sb2));
            const float p3 = __builtin_amdgcn_exp2f(fmaf(sa3[r], SC2, sb3));
            l_r[r] += (p0 + p1) + (p2 + p3);
            unsigned short* pw = &Ps[wid][(quad * 4 + r) * 72 + lq];
            pw[0]  = f2b(p0);
            pw[16] = f2b(p1);
            pw[32] = f2b(p2);
            pw[48] = f2b(p3);
        }

#pragma unroll
        for (int k2 = 0; k2 < 2; ++k2) {
            bf16x8 pf = *(const bf16x8*)&Ps[wid][lq * 72 + k2 * 32 + quad * 8];
            o0 = __builtin_amdgcn_mfma_f32_16x16x32_bf16(
                pf, *(const bf16x8*)&Vt[(0  + lq) * 72 + k2 * 32 + quad * 8], o0, 0, 0, 0);
            o1 = __builtin_amdgcn_mfma_f32_16x16x32_bf16(
                pf, *(const bf16x8*)&Vt[(16 + lq) * 72 + k2 * 32 + quad * 8], o1, 0, 0, 0);
        }
    }

    unsigned short* op = Ctx + (bS + q0 + wid * 16 + quad * 4) * 256 + h * 32;
#pragma unroll
    for (int r = 0; r < 4; ++r) {
        float l = l_r[r];
        l += __shfl_xor(l, 1);
        l += __shfl_xor(l, 2);
        l += __shfl_xor(l, 4);
        l += __shfl_xor(l, 8);
        const float inv = 1.f / l;
        op[r * 256 + lq]      = f2b(o0[r] * inv);
        op[r * 256 + 16 + lq] = f2b(o1[r] * inv);
    }
}

// ---------------- fused residual + LayerNorm (fp32 stream + bf16 copy) ----------------
// NOTE: r and xb may ALIAS (XB == T2). Per-element read-then-write in the same
// thread; no __restrict__ on these args.
__global__ __launch_bounds__(256) void add_ln_kernel(
    const float* x, const unsigned short* r,
    const float* __restrict__ g, const float* __restrict__ be,
    float* out, unsigned short* xb) {
    const int lane = threadIdx.x & 63, wid = threadIdx.x >> 6;
    const size_t row = (size_t)blockIdx.x * 4 + wid;
    float4 xv = *(const float4*)(x + row * 256 + lane * 4);
    uint2 ru = *(const uint2*)(r + row * 256 + lane * 4);
    float2 ra = bpair(ru.x), rb = bpair(ru.y);
    float v[4] = {xv.x + ra.x, xv.y + ra.y, xv.z + rb.x, xv.w + rb.y};
    float sum = v[0] + v[1] + v[2] + v[3];
#pragma unroll
    for (int off = 32; off; off >>= 1) sum += __shfl_xor(sum, off);
    const float mu = sum * (1.f / 256.f);
    float sq = 0.f;
#pragma unroll
    for (int i = 0; i < 4; i++) { float d = v[i] - mu; sq += d * d; }
#pragma unroll
    for (int off = 32; off; off >>= 1) sq += __shfl_xor(sq, off);
    const float rs = rsqrtf(sq * (1.f / 256.f) + 1e-5f);
    float4 o;
    o.x = (v[0] - mu) * rs * g[lane * 4 + 0] + be[lane * 4 + 0];
    o.y = (v[1] - mu) * rs * g[lane * 4 + 1] + be[lane * 4 + 1];
    o.z = (v[2] - mu) * rs * g[lane * 4 + 2] + be[lane * 4 + 2];
    o.w = (v[3] - mu) * rs * g[lane * 4 + 3] + be[lane * 4 + 3];
    *(float4*)(out + row * 256 + lane * 4) = o;
    uint2 p;
    p.x = (unsigned)f2b(o.x) | ((unsigned)f2b(o.y) << 16);
    p.y = (unsigned)f2b(o.z) | ((unsigned)f2b(o.w) << 16);
    *(uint2*)(xb + row * 256 + lane * 4) = p;
}

// ---------------- launch ----------------
extern "C" void kernel_launch(void* const* d_in, const int* in_sizes, int n_in,
                              void* d_out, int out_size, void* d_ws, size_t ws_size,
                              hipStream_t stream) {
    const float* src = (const float*)d_in[0];
    const float* sph = (const float*)d_in[1];
    const float* Wq  = (const float*)d_in[2];
    const float* bq  = (const float*)d_in[3];
    const float* Wk  = (const float*)d_in[4];
    const float* bk  = (const float*)d_in[5];
    const float* Wv  = (const float*)d_in[6];
    const float* bv  = (const float*)d_in[7];
    const float* Wo  = (const float*)d_in[8];
    const float* bo  = (const float*)d_in[9];
    const float* W1  = (const float*)d_in[10];
    const float* b1  = (const float*)d_in[11];
    const float* W2  = (const float*)d_in[12];
    const float* b2  = (const float*)d_in[13];
    const float* g1  = (const float*)d_in[14];
    const float* be1 = (const float*)d_in[15];
    const float* g2  = (const float*)d_in[16];
    const float* be2 = (const float*)d_in[17];

    char* ws = (char*)d_ws;
    float* X = (float*)d_out;                               // fp32 activations in d_out
    unsigned short* QKV = (unsigned short*)(ws + 0);        // 16384 x 768 bf16 (25.2MB)
    unsigned short* CTX = (unsigned short*)(ws + 25165824); // 16384 x 256
    unsigned short* T2  = (unsigned short*)(ws + 33554432); // 16384 x 256 (ALSO = XB)
    unsigned short* H   = QKV;                              // 16384x1024 bf16 reuses QKV+CTX
    unsigned short* XB  = T2;                               // bf16 residual-stream copy (aliased)
    unsigned short* WtQKV = (unsigned short*)(ws + 41943040); // 5 x 768 x 256
    unsigned short* WtO   = (unsigned short*)(ws + 43909120); // 5 x 256 x 256
    unsigned short* Wt1   = (unsigned short*)(ws + 44564480); // 5 x 1024 x 256
    unsigned short* Wt2   = (unsigned short*)(ws + 47185920); // 5 x 256 x 1024
    unsigned short* SPHB  = (unsigned short*)(ws + 50331648); // 8x2048x2048 bf16 (67MB)
    const int use_b16 = (ws_size >= (size_t)117440512);

    const dim3 tb(32, 8);
    transcvt_k<<<dim3(8, 8, 5),  tb, 0, stream>>>(Wq, WtQKV,          256, 256, 65536, 196608);
    transcvt_k<<<dim3(8, 8, 5),  tb, 0, stream>>>(Wk, WtQKV + 65536,  256, 256, 65536, 196608);
    transcvt_k<<<dim3(8, 8, 5),  tb, 0, stream>>>(Wv, WtQKV + 131072, 256, 256, 65536, 196608);
    transcvt_k<<<dim3(8, 8, 5),  tb, 0, stream>>>(Wo, WtO,            256, 256, 65536, 65536);
    transcvt_k<<<dim3(32, 8, 5), tb, 0, stream>>>(W1, Wt1,            256, 1024, 262144, 262144);
    transcvt_k<<<dim3(8, 32, 5), tb, 0, stream>>>(W2, Wt2,            1024, 256, 262144, 262144);
    if (use_b16) sph_cvt<<<16384, 256, 0, stream>>>(sph, SPHB);
    cvt_bf16_k<<<2048, 256, 0, stream>>>(src, XB);   // initial bf16 residual copy

    hipMemcpyAsync(X, src, 16777216, hipMemcpyDeviceToDevice, stream);

    const int M = 16384;
    for (int lyr = 0; lyr < 5; ++lyr) {
        // 1. QKV projection (reads XB=T2; T2 free to clobber afterwards)
        gemm_gl_kernel<128, 1><<<dim3(6, 128), 256, 0, stream>>>(
            XB, WtQKV + lyr * 196608, bq + lyr * 256, bk + lyr * 256, bv + lyr * 256,
            QKV, M, 768, 256, 0);
        // 2. attention
        if (use_b16)
            attn_mfma<1><<<2048, 256, 0, stream>>>(QKV, QKV + 256, QKV + 512, sph, SPHB, CTX);
        else
            attn_mfma<0><<<2048, 256, 0, stream>>>(QKV, QKV + 256, QKV + 512, sph, SPHB, CTX);
        // 3. output projection -> T2 (clobbers XB; old XB already consumed)
        gemm_gl_kernel<64, 0><<<dim3(4, 128), 256, 0, stream>>>(
            CTX, WtO + lyr * 65536, bo + lyr * 256, nullptr, nullptr, T2, M, 256, 256, 0);
        // 4. x = LN(x + T2); writes fp32 X and bf16 XB(=T2, in-place)
        add_ln_kernel<<<4096, 256, 0, stream>>>(X, T2, g1 + lyr * 256, be1 + lyr * 256, X, XB);
        // 5. FFN1 (reads XB) -> H, gelu
        gemm_gl_kernel<128, 0><<<dim3(8, 128), 256, 0, stream>>>(
            XB, Wt1 + lyr * 262144, b1 + lyr * 1024, nullptr, nullptr, H, M, 1024, 256, 1);
        // 6. FFN2 -> T2 (clobbers XB; already consumed by FFN1)
        gemm_gl_kernel<64, 0><<<dim3(4, 128), 256, 0, stream>>>(
            H, Wt2 + lyr * 262144, b2 + lyr * 256, nullptr, nullptr, T2, M, 256, 1024, 0);
        // 7. x = LN(x + T2); refresh XB
        add_ln_kernel<<<4096, 256, 0, stream>>>(X, T2, g2 + lyr * 256, be2 + lyr * 256, X, XB);
    }
}

// Round 6
// 1436.119 us; speedup vs baseline: 1.2437x; 1.0397x over previous
//
#include <hip/hip_runtime.h>
#include <hip/hip_bf16.h>
#include <cstdint>

// ---------------- bf16 helpers ----------------
__device__ __forceinline__ float b2f(unsigned short u) {
    unsigned int t = ((unsigned int)u) << 16;
    float f;
    __builtin_memcpy(&f, &t, 4);
    return f;
}
__device__ __forceinline__ unsigned short f2b(float f) {
    unsigned int u;
    __builtin_memcpy(&u, &f, 4);
    unsigned int r = (u + 0x7FFFu + ((u >> 16) & 1u)) >> 16;
    return (unsigned short)r;
}
// packed f32x2 -> bf16x2 via compiler-lowered v_cvt_pk_bf16_f32 (RNE)
__device__ __forceinline__ unsigned int pkbf(float a, float b) {
    __hip_bfloat162 t = __float22bfloat162_rn(float2{a, b});
    unsigned int u;
    __builtin_memcpy(&u, &t, 4);
    return u;
}
__device__ __forceinline__ float2 bpair(unsigned int u) {
    float2 r;
    unsigned int lo = u << 16;
    unsigned int hi = u & 0xFFFF0000u;
    __builtin_memcpy(&r.x, &lo, 4);
    __builtin_memcpy(&r.y, &hi, 4);
    return r;
}

typedef __attribute__((ext_vector_type(8))) short bf16x8;
typedef __attribute__((ext_vector_type(4))) float f32x4;

#define LOG2E 1.4426950408889634f
#define SC2   0.2550348595f   /* (1/sqrt(32)) * log2(e) */

// 16-byte global -> LDS async copy (LDS dest must be linear: base + lane*16)
__device__ __forceinline__ void gload16(const void* g, void* l) {
    __builtin_amdgcn_global_load_lds(
        (const __attribute__((address_space(1))) unsigned int*)g,
        (__attribute__((address_space(3))) unsigned int*)l, 16, 0, 0);
}

// ---------------- weight transpose + fp32->bf16 convert (once per call) ----------------
__global__ void transcvt_k(const float* __restrict__ in,
                           unsigned short* __restrict__ out, int R, int C,
                           int in_z, int out_z) {
    __shared__ float tile[32][33];
    in += (size_t)blockIdx.z * in_z;
    out += (size_t)blockIdx.z * out_z;
    const int c0 = blockIdx.x * 32, r0 = blockIdx.y * 32;
    const int tx = threadIdx.x, ty = threadIdx.y;
#pragma unroll
    for (int i = 0; i < 32; i += 8)
        tile[ty + i][tx] = in[(size_t)(r0 + ty + i) * C + c0 + tx];
    __syncthreads();
#pragma unroll
    for (int i = 0; i < 32; i += 8)
        out[(size_t)(c0 + ty + i) * R + r0 + tx] = f2b(tile[tx][ty + i]);
}

// ---------------- sph -> bf16 * log2e (once per call) ----------------
__global__ __launch_bounds__(256) void sph_cvt(const float* __restrict__ in,
                                               unsigned short* __restrict__ out) {
    const size_t idx = (size_t)blockIdx.x * 256 + threadIdx.x;
    const float4 a = ((const float4*)in)[idx * 2];
    const float4 b = ((const float4*)in)[idx * 2 + 1];
    uint4 o;
    o.x = pkbf(a.x * LOG2E, a.y * LOG2E);
    o.y = pkbf(a.z * LOG2E, a.w * LOG2E);
    o.z = pkbf(b.x * LOG2E, b.y * LOG2E);
    o.w = pkbf(b.z * LOG2E, b.w * LOG2E);
    ((uint4*)out)[idx] = o;
}

// ---------------- fp32 -> bf16 convert + fp32 copy (initial X / XB) ----------------
__global__ __launch_bounds__(256) void cvt_bf16_k(const float* __restrict__ in,
                                                  unsigned short* __restrict__ out,
                                                  float* __restrict__ xcopy) {
    const size_t idx = (size_t)blockIdx.x * 256 + threadIdx.x;
    const float4 a = ((const float4*)in)[idx * 2];
    const float4 b = ((const float4*)in)[idx * 2 + 1];
    uint4 o;
    o.x = pkbf(a.x, a.y);
    o.y = pkbf(a.z, a.w);
    o.z = pkbf(b.x, b.y);
    o.w = pkbf(b.z, b.w);
    ((uint4*)out)[idx] = o;
    ((float4*)xcopy)[idx * 2] = a;
    ((float4*)xcopy)[idx * 2 + 1] = b;
}

// ---------------- GEMM via global_load_lds: C[M,N] = A[M,K] @ Wt[N,K]^T ----------------
template <int TN, int QKVB>
__global__ __launch_bounds__(256) void gemm_gl_kernel(
    const unsigned short* __restrict__ A, const unsigned short* __restrict__ Wt,
    const float* __restrict__ biasQ, const float* __restrict__ biasK,
    const float* __restrict__ biasV, unsigned short* __restrict__ C,
    int M, int N, int K, int do_gelu) {
    constexpr int JN = TN / 32;          // B frags per wave (per k-half)
    constexpr int NCH = 16 + TN / 8;     // 1KB staging chunks: 16 A + TN/8 B
    __shared__ unsigned short As[128 * 64];
    __shared__ unsigned short Bs[TN * 64];
    const int tid = threadIdx.x;
    const int lane = tid & 63, wid = tid >> 6;
    const int m0 = blockIdx.y * 128, n0 = blockIdx.x * TN;
    const int wm = (wid >> 1) * 64, wn = (wid & 1) * (TN / 2);
    const int quad = lane >> 4, mrow = lane & 15;
    const int lrow = lane >> 3, lslot = lane & 7;
    f32x4 acc[4][JN] = {};

    for (int kb = 0; kb < K; kb += 64) {
#pragma unroll
        for (int cc = 0; cc < NCH / 4; ++cc) {
            const int c = wid * (NCH / 4) + cc;    // wave-uniform chunk id
            if (c < 16) {
                const int row = c * 8 + lrow;
                const int gcol = ((lslot ^ (row & 7)) << 3) + kb;
                gload16(A + (size_t)(m0 + row) * K + gcol, &As[c * 512 + lane * 8]);
            } else {
                const int row = (c - 16) * 8 + lrow;
                const int gcol = ((lslot ^ (row & 7)) << 3) + kb;
                gload16(Wt + (size_t)(n0 + row) * K + gcol, &Bs[(c - 16) * 512 + lane * 8]);
            }
        }
        __syncthreads();   // compiler drains vmcnt(0) here (m97 structure)
#pragma unroll
        for (int h = 0; h < 2; ++h) {
            bf16x8 af[4], bfr[JN];
#pragma unroll
            for (int i = 0; i < 4; i++) {
                const int ar = wm + i * 16 + mrow;
                af[i] = *(const bf16x8*)&As[ar * 64 + (((h * 4 + quad) ^ (ar & 7)) << 3)];
            }
#pragma unroll
            for (int j = 0; j < JN; j++) {
                const int br = wn + j * 16 + mrow;
                bfr[j] = *(const bf16x8*)&Bs[br * 64 + (((h * 4 + quad) ^ (br & 7)) << 3)];
            }
#pragma unroll
            for (int i = 0; i < 4; i++)
#pragma unroll
                for (int j = 0; j < JN; j++)
                    acc[i][j] = __builtin_amdgcn_mfma_f32_16x16x32_bf16(af[i], bfr[j], acc[i][j], 0, 0, 0);
        }
        __syncthreads();
    }

    const float* bp;
    if (QKVB) {
        const int bsel = n0 >> 8;
        bp = bsel == 0 ? biasQ : (bsel == 1 ? biasK : biasV);
    } else {
        bp = biasQ;
    }
#pragma unroll
    for (int i = 0; i < 4; i++)
#pragma unroll
        for (int j = 0; j < JN; j++) {
            const int col = n0 + wn + j * 16 + mrow;
            const float bv = QKVB ? bp[col & 255] : bp[col];
#pragma unroll
            for (int r = 0; r < 4; r++) {
                const int row = m0 + wm + i * 16 + quad * 4 + r;
                float v = acc[i][j][r] + bv;
                if (do_gelu) v = 0.5f * v * (1.0f + erff(v * 0.70710678118654752f));
                C[(size_t)row * N + col] = f2b(v);
            }
        }
}

// ---------------- attention: flash-style MFMA, no-max exp2 softmax ----------------
// Round-0 structure. Changes:
//  * XCD swizzle: all (b,qt) blocks of one head on one XCD -> K/V L2-resident.
//  * P stored in "slot" order (slot = 2*(k&15) + (k>>4&1) + 32*(k>>5)) so the
//    (p0,p1)/(p2,p3) pairs pack with v_cvt_pk_bf16_f32 + single ds_write_b32.
//    Vt's key axis uses the SAME slot order (MFMA k-permutation cancels).
//  * s_setprio(1) around MFMA clusters (T5).
template <int SPHB16>
__global__ __launch_bounds__(256) void attn_mfma(
    const unsigned short* __restrict__ Qb, const unsigned short* __restrict__ Kb,
    const unsigned short* __restrict__ Vb, const float* __restrict__ sphf,
    const unsigned short* __restrict__ sphb, unsigned short* __restrict__ Ctx) {
    __shared__ unsigned short Ks[64 * 40];
    __shared__ unsigned short Vt[32 * 72];
    __shared__ unsigned short Ps[4][16 * 72];

    const int tid = threadIdx.x, lane = tid & 63, wid = tid >> 6;
    const int quad = lane >> 4, lq = lane & 15;
    const int bid0 = blockIdx.x;
    const int bid = (bid0 & 7) * 256 + (bid0 >> 3);   // XCD-contiguous head chunks
    const int h = bid >> 8, b = (bid >> 5) & 7, qt = bid & 31;
    const int q0 = qt * 64;
    const size_t bS = (size_t)b * 2048;

    // K staging (unchanged layout)
    const int skey = tid >> 2, sdg = (tid & 3) << 3;
    const unsigned short* kp = Kb + (bS + skey) * 768 + h * 32 + sdg;
    // V staging in slot order: thread vkp handles keys (m+32c, m+32c+16)
    const int vkp = tid & 31, vdg = (tid >> 5) << 2;
    const int vm = vkp & 15, vc = vkp >> 4;
    const int vso = 2 * vm + 32 * vc;                 // short offset within Vt row
    const unsigned short* vp = Vb + (bS + vm + 32 * vc) * 768 + h * 32 + vdg;

    const bf16x8 qf = *(const bf16x8*)(Qb + (bS + q0 + wid * 16 + lq) * 768 + h * 32 + quad * 8);

    const size_t sprow = ((size_t)b * 2048 + q0 + wid * 16 + quad * 4) * 2048 + lq;
    const float* spf = sphf + sprow;
    const unsigned short* spb = sphb + sprow;

    float l_r[4] = {0.f, 0.f, 0.f, 0.f};
    f32x4 o0 = {}, o1 = {};

    for (int kt = 0; kt < 32; ++kt) {
        __syncthreads();                        // protect Ks/Vt reuse
        *(uint4*)&Ks[skey * 40 + sdg] = *(const uint4*)kp;
        {
            uint2 va  = *(const uint2*)vp;                 // key m+32c
            uint2 vb2 = *(const uint2*)(vp + 16 * 768);    // key m+32c+16
            *(unsigned int*)&Vt[(vdg + 0) * 72 + vso] = (va.x & 0xFFFFu) | (vb2.x << 16);
            *(unsigned int*)&Vt[(vdg + 1) * 72 + vso] = (va.x >> 16) | (vb2.x & 0xFFFF0000u);
            *(unsigned int*)&Vt[(vdg + 2) * 72 + vso] = (va.y & 0xFFFFu) | (vb2.y << 16);
            *(unsigned int*)&Vt[(vdg + 3) * 72 + vso] = (va.y >> 16) | (vb2.y & 0xFFFF0000u);
        }
        kp += 64 * 768;
        vp += 64 * 768;
        __syncthreads();

        const f32x4 zf = {};
        __builtin_amdgcn_s_setprio(1);
        f32x4 sa0 = __builtin_amdgcn_mfma_f32_16x16x32_bf16(
            qf, *(const bf16x8*)&Ks[(0  + lq) * 40 + quad * 8], zf, 0, 0, 0);
        f32x4 sa1 = __builtin_amdgcn_mfma_f32_16x16x32_bf16(
            qf, *(const bf16x8*)&Ks[(16 + lq) * 40 + quad * 8], zf, 0, 0, 0);
        f32x4 sa2 = __builtin_amdgcn_mfma_f32_16x16x32_bf16(
            qf, *(const bf16x8*)&Ks[(32 + lq) * 40 + quad * 8], zf, 0, 0, 0);
        f32x4 sa3 = __builtin_amdgcn_mfma_f32_16x16x32_bf16(
            qf, *(const bf16x8*)&Ks[(48 + lq) * 40 + quad * 8], zf, 0, 0, 0);
        __builtin_amdgcn_s_setprio(0);

        // p = exp2(qk*SC2 + sph*log2e); l per-lane; P -> LDS in slot order
        const int k0 = kt * 64;
#pragma unroll
        for (int r = 0; r < 4; ++r) {
            float sb0, sb1, sb2, sb3;
            if (SPHB16) {
                const unsigned short* spr = spb + (size_t)r * 2048 + k0;
                sb0 = b2f(spr[0]);  sb1 = b2f(spr[16]);
                sb2 = b2f(spr[32]); sb3 = b2f(spr[48]);
            } else {
                const float* spr = spf + (size_t)r * 2048 + k0;
                sb0 = spr[0]  * LOG2E; sb1 = spr[16] * LOG2E;
                sb2 = spr[32] * LOG2E; sb3 = spr[48] * LOG2E;
            }
            const float p0 = __builtin_amdgcn_exp2f(fmaf(sa0[r], SC2, sb0));
            const float p1 = __builtin_amdgcn_exp2f(fmaf(sa1[r], SC2, sb1));
            const float p2 = __builtin_amdgcn_exp2f(fmaf(sa2[r], SC2, sb2));
            const float p3 = __builtin_amdgcn_exp2f(fmaf(sa3[r], SC2, sb3));
            l_r[r] += (p0 + p1) + (p2 + p3);
            unsigned int* pw = (unsigned int*)&Ps[wid][(quad * 4 + r) * 72];
            pw[lq]      = pkbf(p0, p1);   // slots 2lq, 2lq+1   (keys lq, lq+16)
            pw[lq + 16] = pkbf(p2, p3);   // slots 2lq+32,+33   (keys lq+32, lq+48)
        }

        // PV: P and Vt share the same key-slot permutation
        __builtin_amdgcn_s_setprio(1);
#pragma unroll
        for (int k2 = 0; k2 < 2; ++k2) {
            bf16x8 pf = *(const bf16x8*)&Ps[wid][lq * 72 + k2 * 32 + quad * 8];
            o0 = __builtin_amdgcn_mfma_f32_16x16x32_bf16(
                pf, *(const bf16x8*)&Vt[(0  + lq) * 72 + k2 * 32 + quad * 8], o0, 0, 0, 0);
            o1 = __builtin_amdgcn_mfma_f32_16x16x32_bf16(
                pf, *(const bf16x8*)&Vt[(16 + lq) * 72 + k2 * 32 + quad * 8], o1, 0, 0, 0);
        }
        __builtin_amdgcn_s_setprio(0);
    }

    unsigned short* op = Ctx + (bS + q0 + wid * 16 + quad * 4) * 256 + h * 32;
#pragma unroll
    for (int r = 0; r < 4; ++r) {
        float l = l_r[r];
        l += __shfl_xor(l, 1);
        l += __shfl_xor(l, 2);
        l += __shfl_xor(l, 4);
        l += __shfl_xor(l, 8);
        const float inv = 1.f / l;
        op[r * 256 + lq]      = f2b(o0[r] * inv);
        op[r * 256 + 16 + lq] = f2b(o1[r] * inv);
    }
}

// ---------------- fused residual + LayerNorm (fp32 stream + bf16 copy) ----------------
// NOTE: r and xb may ALIAS (XB == T2). Per-element read-then-write in the same
// thread; no __restrict__ on these args.
__global__ __launch_bounds__(256) void add_ln_kernel(
    const float* x, const unsigned short* r,
    const float* __restrict__ g, const float* __restrict__ be,
    float* out, unsigned short* xb) {
    const int lane = threadIdx.x & 63, wid = threadIdx.x >> 6;
    const size_t row = (size_t)blockIdx.x * 4 + wid;
    float4 xv = *(const float4*)(x + row * 256 + lane * 4);
    uint2 ru = *(const uint2*)(r + row * 256 + lane * 4);
    float2 ra = bpair(ru.x), rb = bpair(ru.y);
    float v[4] = {xv.x + ra.x, xv.y + ra.y, xv.z + rb.x, xv.w + rb.y};
    float sum = v[0] + v[1] + v[2] + v[3];
#pragma unroll
    for (int off = 32; off; off >>= 1) sum += __shfl_xor(sum, off);
    const float mu = sum * (1.f / 256.f);
    float sq = 0.f;
#pragma unroll
    for (int i = 0; i < 4; i++) { float d = v[i] - mu; sq += d * d; }
#pragma unroll
    for (int off = 32; off; off >>= 1) sq += __shfl_xor(sq, off);
    const float rs = rsqrtf(sq * (1.f / 256.f) + 1e-5f);
    float4 o;
    o.x = (v[0] - mu) * rs * g[lane * 4 + 0] + be[lane * 4 + 0];
    o.y = (v[1] - mu) * rs * g[lane * 4 + 1] + be[lane * 4 + 1];
    o.z = (v[2] - mu) * rs * g[lane * 4 + 2] + be[lane * 4 + 2];
    o.w = (v[3] - mu) * rs * g[lane * 4 + 3] + be[lane * 4 + 3];
    *(float4*)(out + row * 256 + lane * 4) = o;
    uint2 p;
    p.x = pkbf(o.x, o.y);
    p.y = pkbf(o.z, o.w);
    *(uint2*)(xb + row * 256 + lane * 4) = p;
}

// ---------------- launch ----------------
extern "C" void kernel_launch(void* const* d_in, const int* in_sizes, int n_in,
                              void* d_out, int out_size, void* d_ws, size_t ws_size,
                              hipStream_t stream) {
    const float* src = (const float*)d_in[0];
    const float* sph = (const float*)d_in[1];
    const float* Wq  = (const float*)d_in[2];
    const float* bq  = (const float*)d_in[3];
    const float* Wk  = (const float*)d_in[4];
    const float* bk  = (const float*)d_in[5];
    const float* Wv  = (const float*)d_in[6];
    const float* bv  = (const float*)d_in[7];
    const float* Wo  = (const float*)d_in[8];
    const float* bo  = (const float*)d_in[9];
    const float* W1  = (const float*)d_in[10];
    const float* b1  = (const float*)d_in[11];
    const float* W2  = (const float*)d_in[12];
    const float* b2  = (const float*)d_in[13];
    const float* g1  = (const float*)d_in[14];
    const float* be1 = (const float*)d_in[15];
    const float* g2  = (const float*)d_in[16];
    const float* be2 = (const float*)d_in[17];

    char* ws = (char*)d_ws;
    float* X = (float*)d_out;                               // fp32 activations in d_out
    unsigned short* QKV = (unsigned short*)(ws + 0);        // 16384 x 768 bf16 (25.2MB)
    unsigned short* CTX = (unsigned short*)(ws + 25165824); // 16384 x 256
    unsigned short* T2  = (unsigned short*)(ws + 33554432); // 16384 x 256 (ALSO = XB)
    unsigned short* H   = QKV;                              // 16384x1024 bf16 reuses QKV+CTX
    unsigned short* XB  = T2;                               // bf16 residual-stream copy (aliased)
    unsigned short* WtQKV = (unsigned short*)(ws + 41943040); // 5 x 768 x 256
    unsigned short* WtO   = (unsigned short*)(ws + 43909120); // 5 x 256 x 256
    unsigned short* Wt1   = (unsigned short*)(ws + 44564480); // 5 x 1024 x 256
    unsigned short* Wt2   = (unsigned short*)(ws + 47185920); // 5 x 256 x 1024
    unsigned short* SPHB  = (unsigned short*)(ws + 50331648); // 8x2048x2048 bf16 (67MB)
    const int use_b16 = (ws_size >= (size_t)117440512);

    const dim3 tb(32, 8);
    transcvt_k<<<dim3(8, 8, 5),  tb, 0, stream>>>(Wq, WtQKV,          256, 256, 65536, 196608);
    transcvt_k<<<dim3(8, 8, 5),  tb, 0, stream>>>(Wk, WtQKV + 65536,  256, 256, 65536, 196608);
    transcvt_k<<<dim3(8, 8, 5),  tb, 0, stream>>>(Wv, WtQKV + 131072, 256, 256, 65536, 196608);
    transcvt_k<<<dim3(8, 8, 5),  tb, 0, stream>>>(Wo, WtO,            256, 256, 65536, 65536);
    transcvt_k<<<dim3(32, 8, 5), tb, 0, stream>>>(W1, Wt1,            256, 1024, 262144, 262144);
    transcvt_k<<<dim3(8, 32, 5), tb, 0, stream>>>(W2, Wt2,            1024, 256, 262144, 262144);
    if (use_b16) sph_cvt<<<16384, 256, 0, stream>>>(sph, SPHB);
    cvt_bf16_k<<<2048, 256, 0, stream>>>(src, XB, X);  // bf16 copy + fp32 copy fused

    const int M = 16384;
    for (int lyr = 0; lyr < 5; ++lyr) {
        // 1. QKV projection (reads XB=T2; T2 free to clobber afterwards)
        gemm_gl_kernel<128, 1><<<dim3(6, 128), 256, 0, stream>>>(
            XB, WtQKV + lyr * 196608, bq + lyr * 256, bk + lyr * 256, bv + lyr * 256,
            QKV, M, 768, 256, 0);
        // 2. attention
        if (use_b16)
            attn_mfma<1><<<2048, 256, 0, stream>>>(QKV, QKV + 256, QKV + 512, sph, SPHB, CTX);
        else
            attn_mfma<0><<<2048, 256, 0, stream>>>(QKV, QKV + 256, QKV + 512, sph, SPHB, CTX);
        // 3. output projection -> T2 (clobbers XB; old XB already consumed)
        gemm_gl_kernel<64, 0><<<dim3(4, 128), 256, 0, stream>>>(
            CTX, WtO + lyr * 65536, bo + lyr * 256, nullptr, nullptr, T2, M, 256, 256, 0);
        // 4. x = LN(x + T2); writes fp32 X and bf16 XB(=T2, in-place)
        add_ln_kernel<<<4096, 256, 0, stream>>>(X, T2, g1 + lyr * 256, be1 + lyr * 256, X, XB);
        // 5. FFN1 (reads XB) -> H, gelu
        gemm_gl_kernel<128, 0><<<dim3(8, 128), 256, 0, stream>>>(
            XB, Wt1 + lyr * 262144, b1 + lyr * 1024, nullptr, nullptr, H, M, 1024, 256, 1);
        // 6. FFN2 -> T2 (clobbers XB; already consumed by FFN1)
        gemm_gl_kernel<64, 0><<<dim3(4, 128), 256, 0, stream>>>(
            H, Wt2 + lyr * 262144, b2 + lyr * 256, nullptr, nullptr, T2, M, 256, 1024, 0);
        // 7. x = LN(x + T2); refresh XB
        add_ln_kernel<<<4096, 256, 0, stream>>>(X, T2, g2 + lyr * 256, be2 + lyr * 256, X, XB);
    }
}

// Round 7
// 1409.727 us; speedup vs baseline: 1.2669x; 1.0187x over previous
//
#include <hip/hip_runtime.h>
#include <hip/hip_bf16.h>
#include <cstdint>

// ---------------- bf16 helpers ----------------
__device__ __forceinline__ float b2f(unsigned short u) {
    unsigned int t = ((unsigned int)u) << 16;
    float f;
    __builtin_memcpy(&f, &t, 4);
    return f;
}
__device__ __forceinline__ unsigned short f2b(float f) {
    unsigned int u;
    __builtin_memcpy(&u, &f, 4);
    unsigned int r = (u + 0x7FFFu + ((u >> 16) & 1u)) >> 16;
    return (unsigned short)r;
}
// packed f32x2 -> bf16x2 via compiler-lowered v_cvt_pk_bf16_f32 (RNE)
__device__ __forceinline__ unsigned int pkbf(float a, float b) {
    __hip_bfloat162 t = __float22bfloat162_rn(float2{a, b});
    unsigned int u;
    __builtin_memcpy(&u, &t, 4);
    return u;
}
__device__ __forceinline__ float2 bpair(unsigned int u) {
    float2 r;
    unsigned int lo = u << 16;
    unsigned int hi = u & 0xFFFF0000u;
    __builtin_memcpy(&r.x, &lo, 4);
    __builtin_memcpy(&r.y, &hi, 4);
    return r;
}

typedef __attribute__((ext_vector_type(8))) short bf16x8;
typedef __attribute__((ext_vector_type(4))) float f32x4;

#define LOG2E 1.4426950408889634f
#define SC2   0.2550348595f   /* (1/sqrt(32)) * log2(e) */

// 16-byte global -> LDS async copy (LDS dest must be linear: base + lane*16)
__device__ __forceinline__ void gload16(const void* g, void* l) {
    __builtin_amdgcn_global_load_lds(
        (const __attribute__((address_space(1))) unsigned int*)g,
        (__attribute__((address_space(3))) unsigned int*)l, 16, 0, 0);
}

// ---------------- weight transpose + fp32->bf16 convert (once per call) ----------------
__global__ void transcvt_k(const float* __restrict__ in,
                           unsigned short* __restrict__ out, int R, int C,
                           int in_z, int out_z) {
    __shared__ float tile[32][33];
    in += (size_t)blockIdx.z * in_z;
    out += (size_t)blockIdx.z * out_z;
    const int c0 = blockIdx.x * 32, r0 = blockIdx.y * 32;
    const int tx = threadIdx.x, ty = threadIdx.y;
#pragma unroll
    for (int i = 0; i < 32; i += 8)
        tile[ty + i][tx] = in[(size_t)(r0 + ty + i) * C + c0 + tx];
    __syncthreads();
#pragma unroll
    for (int i = 0; i < 32; i += 8)
        out[(size_t)(c0 + ty + i) * R + r0 + tx] = f2b(tile[tx][ty + i]);
}

// ---------------- sph -> bf16 * log2e, key-permuted within 64-tiles ----------------
// Within each 64-key tile, key k is stored at slot 4*(k&15) + ((k>>4)&3), so a
// lane's 4 bias values {lq, lq+16, lq+32, lq+48} are one contiguous uint2.
// Thread layout: 2 rows/block; t = tid&127 -> tile g = t>>2, quarter q = t&3.
// Reads 4x float4 (cols 64g+16j+4q..+3), writes 2x uint4 (slots 16q..16q+15).
__global__ __launch_bounds__(256) void sph_cvt_perm(const float* __restrict__ in,
                                                    unsigned short* __restrict__ out) {
    const int t = threadIdx.x & 127;
    const size_t row = (size_t)blockIdx.x * 2 + (threadIdx.x >> 7);
    const int g = t >> 2, q = t & 3;
    const float* ip = in + row * 2048 + 64 * g + 4 * q;
    float4 f0 = *(const float4*)(ip);
    float4 f1 = *(const float4*)(ip + 16);
    float4 f2 = *(const float4*)(ip + 32);
    float4 f3 = *(const float4*)(ip + 48);
    uint4 o0, o1;
    o0.x = pkbf(f0.x * LOG2E, f1.x * LOG2E); o0.y = pkbf(f2.x * LOG2E, f3.x * LOG2E);
    o0.z = pkbf(f0.y * LOG2E, f1.y * LOG2E); o0.w = pkbf(f2.y * LOG2E, f3.y * LOG2E);
    o1.x = pkbf(f0.z * LOG2E, f1.z * LOG2E); o1.y = pkbf(f2.z * LOG2E, f3.z * LOG2E);
    o1.z = pkbf(f0.w * LOG2E, f1.w * LOG2E); o1.w = pkbf(f2.w * LOG2E, f3.w * LOG2E);
    unsigned short* op = out + row * 2048 + 64 * g + 16 * q;
    ((uint4*)op)[0] = o0;
    ((uint4*)op)[1] = o1;
}

// ---------------- fp32 -> bf16 convert + fp32 copy (initial X / XB) ----------------
__global__ __launch_bounds__(256) void cvt_bf16_k(const float* __restrict__ in,
                                                  unsigned short* __restrict__ out,
                                                  float* __restrict__ xcopy) {
    const size_t idx = (size_t)blockIdx.x * 256 + threadIdx.x;
    const float4 a = ((const float4*)in)[idx * 2];
    const float4 b = ((const float4*)in)[idx * 2 + 1];
    uint4 o;
    o.x = pkbf(a.x, a.y);
    o.y = pkbf(a.z, a.w);
    o.z = pkbf(b.x, b.y);
    o.w = pkbf(b.z, b.w);
    ((uint4*)out)[idx] = o;
    ((float4*)xcopy)[idx * 2] = a;
    ((float4*)xcopy)[idx * 2 + 1] = b;
}

// ---------------- GEMM via global_load_lds: C[M,N] = A[M,K] @ Wt[N,K]^T ----------------
template <int TN, int QKVB>
__global__ __launch_bounds__(256) void gemm_gl_kernel(
    const unsigned short* __restrict__ A, const unsigned short* __restrict__ Wt,
    const float* __restrict__ biasQ, const float* __restrict__ biasK,
    const float* __restrict__ biasV, unsigned short* __restrict__ C,
    int M, int N, int K, int do_gelu) {
    constexpr int JN = TN / 32;          // B frags per wave (per k-half)
    constexpr int NCH = 16 + TN / 8;     // 1KB staging chunks: 16 A + TN/8 B
    __shared__ unsigned short As[128 * 64];
    __shared__ unsigned short Bs[TN * 64];
    const int tid = threadIdx.x;
    const int lane = tid & 63, wid = tid >> 6;
    const int m0 = blockIdx.y * 128, n0 = blockIdx.x * TN;
    const int wm = (wid >> 1) * 64, wn = (wid & 1) * (TN / 2);
    const int quad = lane >> 4, mrow = lane & 15;
    const int lrow = lane >> 3, lslot = lane & 7;
    f32x4 acc[4][JN] = {};

    for (int kb = 0; kb < K; kb += 64) {
#pragma unroll
        for (int cc = 0; cc < NCH / 4; ++cc) {
            const int c = wid * (NCH / 4) + cc;    // wave-uniform chunk id
            if (c < 16) {
                const int row = c * 8 + lrow;
                const int gcol = ((lslot ^ (row & 7)) << 3) + kb;
                gload16(A + (size_t)(m0 + row) * K + gcol, &As[c * 512 + lane * 8]);
            } else {
                const int row = (c - 16) * 8 + lrow;
                const int gcol = ((lslot ^ (row & 7)) << 3) + kb;
                gload16(Wt + (size_t)(n0 + row) * K + gcol, &Bs[(c - 16) * 512 + lane * 8]);
            }
        }
        __syncthreads();   // compiler drains vmcnt(0) here (m97 structure)
#pragma unroll
        for (int h = 0; h < 2; ++h) {
            bf16x8 af[4], bfr[JN];
#pragma unroll
            for (int i = 0; i < 4; i++) {
                const int ar = wm + i * 16 + mrow;
                af[i] = *(const bf16x8*)&As[ar * 64 + (((h * 4 + quad) ^ (ar & 7)) << 3)];
            }
#pragma unroll
            for (int j = 0; j < JN; j++) {
                const int br = wn + j * 16 + mrow;
                bfr[j] = *(const bf16x8*)&Bs[br * 64 + (((h * 4 + quad) ^ (br & 7)) << 3)];
            }
#pragma unroll
            for (int i = 0; i < 4; i++)
#pragma unroll
                for (int j = 0; j < JN; j++)
                    acc[i][j] = __builtin_amdgcn_mfma_f32_16x16x32_bf16(af[i], bfr[j], acc[i][j], 0, 0, 0);
        }
        __syncthreads();
    }

    const float* bp;
    if (QKVB) {
        const int bsel = n0 >> 8;
        bp = bsel == 0 ? biasQ : (bsel == 1 ? biasK : biasV);
    } else {
        bp = biasQ;
    }
#pragma unroll
    for (int i = 0; i < 4; i++)
#pragma unroll
        for (int j = 0; j < JN; j++) {
            const int col = n0 + wn + j * 16 + mrow;
            const float bv = QKVB ? bp[col & 255] : bp[col];
#pragma unroll
            for (int r = 0; r < 4; r++) {
                const int row = m0 + wm + i * 16 + quad * 4 + r;
                float v = acc[i][j][r] + bv;
                if (do_gelu) v = 0.5f * v * (1.0f + erff(v * 0.70710678118654752f));
                C[(size_t)row * N + col] = f2b(v);
            }
        }
}

// ---------------- attention: flash MFMA, T14 double-buffered staging ----------------
// One barrier per k-tile: {store prefetched regs -> buf[c]; issue loads kt+1;
// barrier; compute buf[c]}. Global latency hides under the compute phase.
// sph bias (SPHB16 path) read as one uint2/lane/row from the permuted SPHB.
// P in slot order (pkbf pairs); Vt key axis uses the same slot permutation.
template <int SPHB16>
__global__ __launch_bounds__(256) void attn_mfma(
    const unsigned short* __restrict__ Qb, const unsigned short* __restrict__ Kb,
    const unsigned short* __restrict__ Vb, const float* __restrict__ sphf,
    const unsigned short* __restrict__ sphb, unsigned short* __restrict__ Ctx) {
    __shared__ unsigned short Ks[2 * 64 * 40];
    __shared__ unsigned short Vt[2 * 32 * 72];
    __shared__ unsigned short Ps[4][16 * 72];

    const int tid = threadIdx.x, lane = tid & 63, wid = tid >> 6;
    const int quad = lane >> 4, lq = lane & 15;
    const int bid = blockIdx.x;                       // default order: sph-sharers same XCD
    const int h = bid >> 8, b = (bid >> 5) & 7, qt = bid & 31;
    const int q0 = qt * 64;
    const size_t bS = (size_t)b * 2048;

    // K staging
    const int skey = tid >> 2, sdg = (tid & 3) << 3;
    const unsigned short* kp = Kb + (bS + skey) * 768 + h * 32 + sdg;
    // V staging in slot order: thread vkp handles keys (m+32c, m+32c+16)
    const int vkp = tid & 31, vdg = (tid >> 5) << 2;
    const int vm = vkp & 15, vc = vkp >> 4;
    const int vso = 2 * vm + 32 * vc;                 // short offset within Vt row
    const unsigned short* vp = Vb + (bS + vm + 32 * vc) * 768 + h * 32 + vdg;

    const bf16x8 qf = *(const bf16x8*)(Qb + (bS + q0 + wid * 16 + lq) * 768 + h * 32 + quad * 8);

    // sph bases: permuted bf16 path uses 4*lq slot offset; fp32 path uses lq
    const size_t sprow = ((size_t)b * 2048 + q0 + wid * 16 + quad * 4) * 2048;
    const float* spf = sphf + sprow + lq;
    const unsigned short* spb = sphb + sprow + 4 * lq;

    float l_r[4] = {0.f, 0.f, 0.f, 0.f};
    f32x4 o0 = {}, o1 = {};

    // prologue: prefetch tile 0
    uint4 kw = *(const uint4*)kp;
    uint2 va = *(const uint2*)vp;
    uint2 vb2 = *(const uint2*)(vp + 16 * 768);
    int c = 0;

    for (int kt = 0; kt < 32; ++kt) {
        // store prefetched tile into buf[c] (last read of buf[c] was kt-2,
        // separated by barrier(kt-1) -> safe with single barrier/iter)
        *(uint4*)&Ks[c * 2560 + skey * 40 + sdg] = kw;
        {
            unsigned short* vt = &Vt[c * 2304];
            *(unsigned int*)&vt[(vdg + 0) * 72 + vso] = (va.x & 0xFFFFu) | (vb2.x << 16);
            *(unsigned int*)&vt[(vdg + 1) * 72 + vso] = (va.x >> 16) | (vb2.x & 0xFFFF0000u);
            *(unsigned int*)&vt[(vdg + 2) * 72 + vso] = (va.y & 0xFFFFu) | (vb2.y << 16);
            *(unsigned int*)&vt[(vdg + 3) * 72 + vso] = (va.y >> 16) | (vb2.y & 0xFFFF0000u);
        }
        // issue next tile's global loads; latency hides under compute below
        if (kt < 31) {
            kp += 64 * 768;
            vp += 64 * 768;
            kw = *(const uint4*)kp;
            va = *(const uint2*)vp;
            vb2 = *(const uint2*)(vp + 16 * 768);
        }
        __syncthreads();

        const unsigned short* ks = &Ks[c * 2560];
        const unsigned short* vt = &Vt[c * 2304];
        const f32x4 zf = {};
        __builtin_amdgcn_s_setprio(1);
        f32x4 sa0 = __builtin_amdgcn_mfma_f32_16x16x32_bf16(
            qf, *(const bf16x8*)&ks[(0  + lq) * 40 + quad * 8], zf, 0, 0, 0);
        f32x4 sa1 = __builtin_amdgcn_mfma_f32_16x16x32_bf16(
            qf, *(const bf16x8*)&ks[(16 + lq) * 40 + quad * 8], zf, 0, 0, 0);
        f32x4 sa2 = __builtin_amdgcn_mfma_f32_16x16x32_bf16(
            qf, *(const bf16x8*)&ks[(32 + lq) * 40 + quad * 8], zf, 0, 0, 0);
        f32x4 sa3 = __builtin_amdgcn_mfma_f32_16x16x32_bf16(
            qf, *(const bf16x8*)&ks[(48 + lq) * 40 + quad * 8], zf, 0, 0, 0);
        __builtin_amdgcn_s_setprio(0);

        // p = exp2(qk*SC2 + sph*log2e); l per-lane; P -> LDS in slot order
        const int k0 = kt * 64;
#pragma unroll
        for (int r = 0; r < 4; ++r) {
            float sb0, sb1, sb2, sb3;
            if (SPHB16) {
                const uint2 su = *(const uint2*)(spb + (size_t)r * 2048 + k0);
                const float2 slo = bpair(su.x), shi = bpair(su.y);
                sb0 = slo.x; sb1 = slo.y; sb2 = shi.x; sb3 = shi.y;
            } else {
                const float* spr = spf + (size_t)r * 2048 + k0;
                sb0 = spr[0]  * LOG2E; sb1 = spr[16] * LOG2E;
                sb2 = spr[32] * LOG2E; sb3 = spr[48] * LOG2E;
            }
            const float p0 = __builtin_amdgcn_exp2f(fmaf(sa0[r], SC2, sb0));
            const float p1 = __builtin_amdgcn_exp2f(fmaf(sa1[r], SC2, sb1));
            const float p2 = __builtin_amdgcn_exp2f(fmaf(sa2[r], SC2, sb2));
            const float p3 = __builtin_amdgcn_exp2f(fmaf(sa3[r], SC2, sb3));
            l_r[r] += (p0 + p1) + (p2 + p3);
            unsigned int* pw = (unsigned int*)&Ps[wid][(quad * 4 + r) * 72];
            pw[lq]      = pkbf(p0, p1);   // slots 2lq, 2lq+1   (keys lq, lq+16)
            pw[lq + 16] = pkbf(p2, p3);   // slots 2lq+32,+33   (keys lq+32, lq+48)
        }

        // PV: P and Vt share the same key-slot permutation
        __builtin_amdgcn_s_setprio(1);
#pragma unroll
        for (int k2 = 0; k2 < 2; ++k2) {
            bf16x8 pf = *(const bf16x8*)&Ps[wid][lq * 72 + k2 * 32 + quad * 8];
            o0 = __builtin_amdgcn_mfma_f32_16x16x32_bf16(
                pf, *(const bf16x8*)&vt[(0  + lq) * 72 + k2 * 32 + quad * 8], o0, 0, 0, 0);
            o1 = __builtin_amdgcn_mfma_f32_16x16x32_bf16(
                pf, *(const bf16x8*)&vt[(16 + lq) * 72 + k2 * 32 + quad * 8], o1, 0, 0, 0);
        }
        __builtin_amdgcn_s_setprio(0);
        c ^= 1;
    }

    unsigned short* op = Ctx + (bS + q0 + wid * 16 + quad * 4) * 256 + h * 32;
#pragma unroll
    for (int r = 0; r < 4; ++r) {
        float l = l_r[r];
        l += __shfl_xor(l, 1);
        l += __shfl_xor(l, 2);
        l += __shfl_xor(l, 4);
        l += __shfl_xor(l, 8);
        const float inv = 1.f / l;
        op[r * 256 + lq]      = f2b(o0[r] * inv);
        op[r * 256 + 16 + lq] = f2b(o1[r] * inv);
    }
}

// ---------------- fused residual + LayerNorm (fp32 stream + bf16 copy) ----------------
// NOTE: r and xb may ALIAS (XB == T2). Per-element read-then-write in the same
// thread; no __restrict__ on these args.
__global__ __launch_bounds__(256) void add_ln_kernel(
    const float* x, const unsigned short* r,
    const float* __restrict__ g, const float* __restrict__ be,
    float* out, unsigned short* xb) {
    const int lane = threadIdx.x & 63, wid = threadIdx.x >> 6;
    const size_t row = (size_t)blockIdx.x * 4 + wid;
    float4 xv = *(const float4*)(x + row * 256 + lane * 4);
    uint2 ru = *(const uint2*)(r + row * 256 + lane * 4);
    float2 ra = bpair(ru.x), rb = bpair(ru.y);
    float v[4] = {xv.x + ra.x, xv.y + ra.y, xv.z + rb.x, xv.w + rb.y};
    float sum = v[0] + v[1] + v[2] + v[3];
#pragma unroll
    for (int off = 32; off; off >>= 1) sum += __shfl_xor(sum, off);
    const float mu = sum * (1.f / 256.f);
    float sq = 0.f;
#pragma unroll
    for (int i = 0; i < 4; i++) { float d = v[i] - mu; sq += d * d; }
#pragma unroll
    for (int off = 32; off; off >>= 1) sq += __shfl_xor(sq, off);
    const float rs = rsqrtf(sq * (1.f / 256.f) + 1e-5f);
    float4 o;
    o.x = (v[0] - mu) * rs * g[lane * 4 + 0] + be[lane * 4 + 0];
    o.y = (v[1] - mu) * rs * g[lane * 4 + 1] + be[lane * 4 + 1];
    o.z = (v[2] - mu) * rs * g[lane * 4 + 2] + be[lane * 4 + 2];
    o.w = (v[3] - mu) * rs * g[lane * 4 + 3] + be[lane * 4 + 3];
    *(float4*)(out + row * 256 + lane * 4) = o;
    uint2 p;
    p.x = pkbf(o.x, o.y);
    p.y = pkbf(o.z, o.w);
    *(uint2*)(xb + row * 256 + lane * 4) = p;
}

// ---------------- launch ----------------
extern "C" void kernel_launch(void* const* d_in, const int* in_sizes, int n_in,
                              void* d_out, int out_size, void* d_ws, size_t ws_size,
                              hipStream_t stream) {
    const float* src = (const float*)d_in[0];
    const float* sph = (const float*)d_in[1];
    const float* Wq  = (const float*)d_in[2];
    const float* bq  = (const float*)d_in[3];
    const float* Wk  = (const float*)d_in[4];
    const float* bk  = (const float*)d_in[5];
    const float* Wv  = (const float*)d_in[6];
    const float* bv  = (const float*)d_in[7];
    const float* Wo  = (const float*)d_in[8];
    const float* bo  = (const float*)d_in[9];
    const float* W1  = (const float*)d_in[10];
    const float* b1  = (const float*)d_in[11];
    const float* W2  = (const float*)d_in[12];
    const float* b2  = (const float*)d_in[13];
    const float* g1  = (const float*)d_in[14];
    const float* be1 = (const float*)d_in[15];
    const float* g2  = (const float*)d_in[16];
    const float* be2 = (const float*)d_in[17];

    char* ws = (char*)d_ws;
    float* X = (float*)d_out;                               // fp32 activations in d_out
    unsigned short* QKV = (unsigned short*)(ws + 0);        // 16384 x 768 bf16 (25.2MB)
    unsigned short* CTX = (unsigned short*)(ws + 25165824); // 16384 x 256
    unsigned short* T2  = (unsigned short*)(ws + 33554432); // 16384 x 256 (ALSO = XB)
    unsigned short* H   = QKV;                              // 16384x1024 bf16 reuses QKV+CTX
    unsigned short* XB  = T2;                               // bf16 residual-stream copy (aliased)
    unsigned short* WtQKV = (unsigned short*)(ws + 41943040); // 5 x 768 x 256
    unsigned short* WtO   = (unsigned short*)(ws + 43909120); // 5 x 256 x 256
    unsigned short* Wt1   = (unsigned short*)(ws + 44564480); // 5 x 1024 x 256
    unsigned short* Wt2   = (unsigned short*)(ws + 47185920); // 5 x 256 x 1024
    unsigned short* SPHB  = (unsigned short*)(ws + 50331648); // 8x2048x2048 bf16 (67MB), permuted
    const int use_b16 = (ws_size >= (size_t)117440512);

    const dim3 tb(32, 8);
    transcvt_k<<<dim3(8, 8, 5),  tb, 0, stream>>>(Wq, WtQKV,          256, 256, 65536, 196608);
    transcvt_k<<<dim3(8, 8, 5),  tb, 0, stream>>>(Wk, WtQKV + 65536,  256, 256, 65536, 196608);
    transcvt_k<<<dim3(8, 8, 5),  tb, 0, stream>>>(Wv, WtQKV + 131072, 256, 256, 65536, 196608);
    transcvt_k<<<dim3(8, 8, 5),  tb, 0, stream>>>(Wo, WtO,            256, 256, 65536, 65536);
    transcvt_k<<<dim3(32, 8, 5), tb, 0, stream>>>(W1, Wt1,            256, 1024, 262144, 262144);
    transcvt_k<<<dim3(8, 32, 5), tb, 0, stream>>>(W2, Wt2,            1024, 256, 262144, 262144);
    if (use_b16) sph_cvt_perm<<<8192, 256, 0, stream>>>(sph, SPHB);
    cvt_bf16_k<<<2048, 256, 0, stream>>>(src, XB, X);  // bf16 copy + fp32 copy fused

    const int M = 16384;
    for (int lyr = 0; lyr < 5; ++lyr) {
        // 1. QKV projection (reads XB=T2; T2 free to clobber afterwards)
        gemm_gl_kernel<128, 1><<<dim3(6, 128), 256, 0, stream>>>(
            XB, WtQKV + lyr * 196608, bq + lyr * 256, bk + lyr * 256, bv + lyr * 256,
            QKV, M, 768, 256, 0);
        // 2. attention
        if (use_b16)
            attn_mfma<1><<<2048, 256, 0, stream>>>(QKV, QKV + 256, QKV + 512, sph, SPHB, CTX);
        else
            attn_mfma<0><<<2048, 256, 0, stream>>>(QKV, QKV + 256, QKV + 512, sph, SPHB, CTX);
        // 3. output projection -> T2 (clobbers XB; old XB already consumed)
        gemm_gl_kernel<64, 0><<<dim3(4, 128), 256, 0, stream>>>(
            CTX, WtO + lyr * 65536, bo + lyr * 256, nullptr, nullptr, T2, M, 256, 256, 0);
        // 4. x = LN(x + T2); writes fp32 X and bf16 XB(=T2, in-place)
        add_ln_kernel<<<4096, 256, 0, stream>>>(X, T2, g1 + lyr * 256, be1 + lyr * 256, X, XB);
        // 5. FFN1 (reads XB) -> H, gelu
        gemm_gl_kernel<128, 0><<<dim3(8, 128), 256, 0, stream>>>(
            XB, Wt1 + lyr * 262144, b1 + lyr * 1024, nullptr, nullptr, H, M, 1024, 256, 1);
        // 6. FFN2 -> T2 (clobbers XB; already consumed by FFN1)
        gemm_gl_kernel<64, 0><<<dim3(4, 128), 256, 0, stream>>>(
            H, Wt2 + lyr * 262144, b2 + lyr * 256, nullptr, nullptr, T2, M, 256, 1024, 0);
        // 7. x = LN(x + T2); refresh XB
        add_ln_kernel<<<4096, 256, 0, stream>>>(X, T2, g2 + lyr * 256, be2 + lyr * 256, X, XB);
    }
}